// Round 1
// 135.863 us; speedup vs baseline: 1.0233x; 1.0233x over previous
//
#include <hip/hip_runtime.h>
#include <cstdint>
#include <cstddef>

// SelfAttention: B=8, C=256, H=W=32, HEADS=8, hd=32, N=HW=1024
// Pipeline (all bf16 MFMA, fp32 accum):
//   prep:  W[4] fp32->bf16 ; x [b,c,p] fp32 -> xt [b,p,c] bf16 (LDS transpose)
//   qkv :  q (pre-scaled by scale*log2e), k -> [b,h,n,d] bf16 ;
//          v -> [b,c,p] bf16 (m-linear, no interleave)
//   attn:  flash, swapped-operand 32x32x16 form. Per wave: S^T = mfma(K,Q)
//          puts a full P-row per lane (col=n=lane&31). Softmax fully
//          in-register: p=2^s (scale folded into Q, no max needed -- exact
//          after 1/l). P->bf16 via v_cvt_pk_bf16_f32 + v_permlane32_swap
//          (T12 pattern) feeds PV A-operand directly. NO LDS in main loop.
//          SPLIT-M x2: waves 0-1 m[0,512), waves 2-3 m[512,1024); linear
//          combine (no max -> no rescale) through LDS + one __syncthreads.
//   mproj: final projection -> d_out fp32
// ws layout: xt 4MB | Wb 512KB | qt 4MB | kt 4MB | vt 4MB | at 4MB  = 20.5 MB

#define NB 8
#define NC 256
#define NP 1024
#define NHD 8
#define HD 32

typedef short bf16x8 __attribute__((ext_vector_type(8)));
typedef float f32x4 __attribute__((ext_vector_type(4)));
typedef float f32x16 __attribute__((ext_vector_type(16)));

// scale * log2(e) : softmax(s/sqrt(32)) computed as 2^(s*SCLLOG)
#define SCLLOG 0.25505654356918f

#define F32X16_ZERO (f32x16){0.f,0.f,0.f,0.f,0.f,0.f,0.f,0.f,0.f,0.f,0.f,0.f,0.f,0.f,0.f,0.f}

// hardware packed fp32->bf16 (RNE): D.lo = bf16(a), D.hi = bf16(b)
__device__ __forceinline__ unsigned cvt_pk_bf16(float a, float b) {
  unsigned r;
  asm("v_cvt_pk_bf16_f32 %0, %1, %2" : "=v"(r) : "v"(a), "v"(b));
  return r;
}
__device__ __forceinline__ unsigned short f2b1(float a) {
  return (unsigned short)cvt_pk_bf16(a, a);
}

// ---------------- prep: weight cvt + x transpose ----------------
__global__ __launch_bounds__(256) void prep_kernel(
    const float* __restrict__ Wq, const float* __restrict__ Wk,
    const float* __restrict__ Wv, const float* __restrict__ Wm,
    const float* __restrict__ x, unsigned short* __restrict__ Wb,
    unsigned short* __restrict__ xt) {
  __shared__ float sx[64][65];
  int bx = blockIdx.x, tid = threadIdx.x;
  if (bx < 128) {
    int idx = (bx * 256 + tid) * 8;
    const float* src; int off;
    if (idx < 65536)       { src = Wq; off = idx; }
    else if (idx < 131072) { src = Wk; off = idx - 65536; }
    else if (idx < 196608) { src = Wv; off = idx - 131072; }
    else                   { src = Wm; off = idx - 196608; }
    float4 lo = *(const float4*)(src + off);
    float4 hi = *(const float4*)(src + off + 4);
    union { unsigned u[4]; bf16x8 v; } o;
    o.u[0] = cvt_pk_bf16(lo.x, lo.y); o.u[1] = cvt_pk_bf16(lo.z, lo.w);
    o.u[2] = cvt_pk_bf16(hi.x, hi.y); o.u[3] = cvt_pk_bf16(hi.z, hi.w);
    *(bf16x8*)(Wb + idx) = o.v;
  } else {
    // transpose one 64c x 64p tile: x[b,c,p] fp32 -> xt[b,p,c] bf16
    int bi = bx - 128;
    int b = bi >> 6, rest = bi & 63;
    int ct = (rest & 3) * 64, pt = (rest >> 2) * 64;
    const float* xb = x + ((size_t)(b * NC + ct)) * NP + pt;
    int pr = (tid & 15) * 4, cr = tid >> 4;
#pragma unroll
    for (int i = 0; i < 4; i++) {
      float4 v = *(const float4*)(xb + (size_t)(cr + i * 16) * NP + pr);
      sx[cr + i*16][pr]   = v.x; sx[cr + i*16][pr+1] = v.y;
      sx[cr + i*16][pr+2] = v.z; sx[cr + i*16][pr+3] = v.w;
    }
    __syncthreads();
    int pl = tid >> 3, cc = (tid & 7) * 8;
#pragma unroll
    for (int j = 0; j < 2; j++) {
      int p = pl + j * 32;
      union { unsigned u[4]; bf16x8 v; } o;
#pragma unroll
      for (int u = 0; u < 4; u++)
        o.u[u] = cvt_pk_bf16(sx[cc + 2*u][p], sx[cc + 2*u + 1][p]);
      *(bf16x8*)(xt + ((size_t)b * NP + pt + p) * NC + ct + cc) = o.v;
    }
  }
}

// ---------------- QKV projection GEMM ----------------
__global__ __launch_bounds__(256) void qkv_kernel(
    const unsigned short* __restrict__ Wb,
    const float* __restrict__ bq, const float* __restrict__ bk,
    const float* __restrict__ bv,
    const unsigned short* __restrict__ xt,
    unsigned short* __restrict__ qt, unsigned short* __restrict__ kt,
    unsigned short* __restrict__ vt) {
  int proj = blockIdx.z, b = blockIdx.y, bx = blockIdx.x;
  int ot = (bx & 3) * 64, pt = (bx >> 2) * 64;
  int tid = threadIdx.x, wave = tid >> 6, lane = tid & 63;
  int l15 = lane & 15, quad = lane >> 4;
  int oW = ot + (wave & 1) * 32, pW = pt + (wave >> 1) * 32;
  const unsigned short* W = Wb + (size_t)proj * 65536;
  const float* bias = (proj == 0) ? bq : (proj == 1) ? bk : bv;
  // q pre-scaled by scale*log2e so attn's softmax is a bare exp2
  float sc = (proj == 0) ? SCLLOG : 1.0f;
  const unsigned short* A0 = W + (size_t)(oW + l15) * NC + quad * 8;
  const unsigned short* B0 = xt + ((size_t)b * NP + pW + l15) * NC + quad * 8;
  f32x4 acc[2][2];
#pragma unroll
  for (int i = 0; i < 2; i++)
#pragma unroll
    for (int j = 0; j < 2; j++) acc[i][j] = (f32x4){0.f, 0.f, 0.f, 0.f};
#pragma unroll
  for (int c0 = 0; c0 < NC; c0 += 32) {
    bf16x8 a0 = *(const bf16x8*)(A0 + c0);
    bf16x8 a1 = *(const bf16x8*)(A0 + 16 * NC + c0);
    bf16x8 b0 = *(const bf16x8*)(B0 + c0);
    bf16x8 b1 = *(const bf16x8*)(B0 + 16 * NC + c0);
    acc[0][0] = __builtin_amdgcn_mfma_f32_16x16x32_bf16(a0, b0, acc[0][0], 0, 0, 0);
    acc[0][1] = __builtin_amdgcn_mfma_f32_16x16x32_bf16(a0, b1, acc[0][1], 0, 0, 0);
    acc[1][0] = __builtin_amdgcn_mfma_f32_16x16x32_bf16(a1, b0, acc[1][0], 0, 0, 0);
    acc[1][1] = __builtin_amdgcn_mfma_f32_16x16x32_bf16(a1, b1, acc[1][1], 0, 0, 0);
  }
  unsigned short* qk = (proj == 0) ? qt : kt;
#pragma unroll
  for (int rh = 0; rh < 2; rh++) {
    int od0 = oW + rh * 16 + quad * 4;             // 4 consecutive o rows
    float b0 = bias[od0], b1 = bias[od0+1], b2 = bias[od0+2], b3 = bias[od0+3];
#pragma unroll
    for (int ch = 0; ch < 2; ch++) {
      float v0 = acc[rh][ch][0] + b0, v1 = acc[rh][ch][1] + b1;
      float v2 = acc[rh][ch][2] + b2, v3 = acc[rh][ch][3] + b3;
      int p = pW + ch * 16 + l15;
      if (proj < 2) {
        int h2 = od0 >> 5, d0 = od0 & 31;
        uint2 pk;
        pk.x = cvt_pk_bf16(v0 * sc, v1 * sc);
        pk.y = cvt_pk_bf16(v2 * sc, v3 * sc);
        size_t idx = ((size_t)(b * NHD + h2) * NP + p) * HD + d0;
        *(uint2*)(qk + idx) = pk;
      } else {
        // v -> [b, c=o, p] bf16, m-linear (matches PV B-operand k=hi*8+j)
        size_t base = ((size_t)b * NC + od0) * NP + p;
        vt[base]          = f2b1(v0);
        vt[base +     NP] = f2b1(v1);
        vt[base + 2 * NP] = f2b1(v2);
        vt[base + 3 * NP] = f2b1(v3);
      }
    }
  }
}

// ---------------- flash attention (swapped 32x32, split-m) ----------------
// grid (16, 64); block = 256 threads = 4 waves. wsub = wave&1 picks the 32
// q rows (n0 = bx*64 + wsub*32); half = wave>>1 picks the m range
// ([0,512) or [512,1024), 16 tiles of 32 each).
// Per tile: S^T = mfma_32x32x16(K,Q) x2  -> col = n = lane&31,
//   row m = (r&3)+8*(r>>2)+4*hi (crow). p = 2^s in-register; l via VALU adds.
// P->bf16 A-operand: 8 cvt_pk + 4 v_permlane32_swap_b32:
//   w0..w3 = slot0 (m 0..15), w4..w7 = slot1 (m 16..31), k = hi*8+j linear.
// PV: O += mfma(pa0, V[m0..+16]) + mfma(pa1, V[m0+16..+32]); O col = d.
// Combine: linear (no max), half-1 dumps (O,l) to LDS, half-0 adds+stores.
__global__ __launch_bounds__(256, 4) void attn_kernel(
    const unsigned short* __restrict__ qt, const unsigned short* __restrict__ kt,
    const unsigned short* __restrict__ vt, unsigned short* __restrict__ at) {
  int tid = threadIdx.x, wave = tid >> 6, lane = tid & 63;
  int l31 = lane & 31, hi = lane >> 5;
  int half = wave >> 1, wsub = wave & 1;
  int bh = blockIdx.y, b = bh >> 3, h = bh & 7;
  int n0 = blockIdx.x * 64 + wsub * 32;

  __shared__ float Comb[2][64][17];   // [wsub][lane][16 O + 1 l]
  __shared__ float Linv[2][32];       // [wsub][n-in-tile] broadcast of 1/l

  // Q fragments (B-operand): col = n = lane&31, k = d = hi*8+j
  const unsigned short* qp = qt + ((size_t)bh * NP + n0 + l31) * HD + hi * 8;
  bf16x8 qf0 = *(const bf16x8*)(qp);
  bf16x8 qf1 = *(const bf16x8*)(qp + 16);

  // K rows (A-operand): row = m = m0+lane&31, k = d = hi*8+j
  const unsigned short* kp = kt + ((size_t)bh * NP + l31) * HD + hi * 8;
  // V (B-operand): col = d = lane&31, k = m = hi*8+j (m-linear layout)
  const unsigned short* vp = vt + ((size_t)(b * NC + h * HD + l31)) * NP + hi * 8;

  f32x16 oacc = F32X16_ZERO;
  f32x4 la = (f32x4){0.f, 0.f, 0.f, 0.f};

  int mbase = half * 512;
  bf16x8 kf0 = *(const bf16x8*)(kp + (size_t)mbase * HD);
  bf16x8 kf1 = *(const bf16x8*)(kp + (size_t)mbase * HD + 16);
  bf16x8 vf0 = *(const bf16x8*)(vp + mbase);
  bf16x8 vf1 = *(const bf16x8*)(vp + mbase + 16);

  for (int m0 = mbase; m0 < mbase + 512; m0 += 32) {
    f32x16 s = __builtin_amdgcn_mfma_f32_32x32x16_bf16(kf0, qf0, F32X16_ZERO, 0, 0, 0);
    s = __builtin_amdgcn_mfma_f32_32x32x16_bf16(kf1, qf1, s, 0, 0, 0);
    // prefetch next tile (tail over-read lands in the adjacent ws buffer)
    bf16x8 nk0 = *(const bf16x8*)(kp + (size_t)(m0 + 32) * HD);
    bf16x8 nk1 = *(const bf16x8*)(kp + (size_t)(m0 + 32) * HD + 16);
    bf16x8 nv0 = *(const bf16x8*)(vp + m0 + 32);
    bf16x8 nv1 = *(const bf16x8*)(vp + m0 + 48);
    // p = 2^s (scale folded into Q; exact softmax after 1/l, no max needed)
    float p[16];
#pragma unroll
    for (int r = 0; r < 16; r++) p[r] = __builtin_amdgcn_exp2f(s[r]);
#pragma unroll
    for (int r = 0; r < 16; r++) la[r & 3] += p[r];
    // pack P rows to bf16 A-fragments (T12: cvt_pk + permlane32_swap).
    // lo lanes hold m {0-3,8-11,16-19,24-27}, hi lanes the complements.
    unsigned w0 = cvt_pk_bf16(p[0],  p[1]),  w1 = cvt_pk_bf16(p[2],  p[3]);
    unsigned w2 = cvt_pk_bf16(p[4],  p[5]),  w3 = cvt_pk_bf16(p[6],  p[7]);
    unsigned w4 = cvt_pk_bf16(p[8],  p[9]),  w5 = cvt_pk_bf16(p[10], p[11]);
    unsigned w6 = cvt_pk_bf16(p[12], p[13]), w7 = cvt_pk_bf16(p[14], p[15]);
    asm("v_permlane32_swap_b32 %0, %1" : "+v"(w0), "+v"(w2));
    asm("v_permlane32_swap_b32 %0, %1" : "+v"(w1), "+v"(w3));
    asm("v_permlane32_swap_b32 %0, %1" : "+v"(w4), "+v"(w6));
    asm("v_permlane32_swap_b32 %0, %1" : "+v"(w5), "+v"(w7));
    union { unsigned u[4]; bf16x8 v; } pa0, pa1;
    pa0.u[0] = w0; pa0.u[1] = w1; pa0.u[2] = w2; pa0.u[3] = w3;
    pa1.u[0] = w4; pa1.u[1] = w5; pa1.u[2] = w6; pa1.u[3] = w7;
    oacc = __builtin_amdgcn_mfma_f32_32x32x16_bf16(pa0.v, vf0, oacc, 0, 0, 0);
    oacc = __builtin_amdgcn_mfma_f32_32x32x16_bf16(pa1.v, vf1, oacc, 0, 0, 0);
    kf0 = nk0; kf1 = nk1; vf0 = nv0; vf1 = nv1;
  }

  // lane-pair combine of l (lane and lane^32 hold complementary m halves)
  float lsum = (la[0] + la[1]) + (la[2] + la[3]);
  lsum += __shfl_xor(lsum, 32, 64);

  // ---- combine halves (linear: static softmax -> no rescale) ----
  if (half == 1) {
    float* Cb = &Comb[wsub][lane][0];
#pragma unroll
    for (int r = 0; r < 16; r++) Cb[r] = oacc[r];
    Cb[16] = lsum;
  }
  __syncthreads();
  if (half == 0) {
    const float* Cb = &Comb[wsub][lane][0];
#pragma unroll
    for (int r = 0; r < 16; r++) oacc[r] += Cb[r];
    lsum += Cb[16];
    if (hi == 0) Linv[wsub][l31] = 1.0f / lsum;   // same-wave RAW: compiler waits
    // O[n = n0+crow(r,hi), d = l31] -> at[b, n, c = d*8 + h]
    unsigned short* ab = at + (size_t)b * NP * NC + (size_t)(l31 * 8 + h);
#pragma unroll
    for (int r = 0; r < 16; r++) {
      int crow = (r & 3) + 8 * (r >> 2) + 4 * hi;
      float iv = Linv[wsub][crow];                // 2-addr LDS broadcast
      ab[(size_t)(n0 + crow) * NC] = f2b1(oacc[r] * iv);
    }
  }
}

// ---------------- output projection ----------------
__global__ __launch_bounds__(256) void mproj_kernel(
    const unsigned short* __restrict__ Wmb, const float* __restrict__ bm,
    const unsigned short* __restrict__ at, float* __restrict__ out) {
  int b = blockIdx.y, bx = blockIdx.x;
  int ot = (bx & 3) * 64, pt = (bx >> 2) * 64;
  int tid = threadIdx.x, wave = tid >> 6, lane = tid & 63;
  int l15 = lane & 15, quad = lane >> 4;
  int oW = ot + (wave & 1) * 32, pW = pt + (wave >> 1) * 32;
  const unsigned short* A0 = Wmb + (size_t)(oW + l15) * NC + quad * 8;
  const unsigned short* B0 = at + ((size_t)b * NP + pW + l15) * NC + quad * 8;
  f32x4 acc[2][2];
#pragma unroll
  for (int i = 0; i < 2; i++)
#pragma unroll
    for (int j = 0; j < 2; j++) acc[i][j] = (f32x4){0.f, 0.f, 0.f, 0.f};
#pragma unroll
  for (int c0 = 0; c0 < NC; c0 += 32) {
    bf16x8 a0 = *(const bf16x8*)(A0 + c0);
    bf16x8 a1 = *(const bf16x8*)(A0 + 16 * NC + c0);
    bf16x8 b0 = *(const bf16x8*)(B0 + c0);
    bf16x8 b1 = *(const bf16x8*)(B0 + 16 * NC + c0);
    acc[0][0] = __builtin_amdgcn_mfma_f32_16x16x32_bf16(a0, b0, acc[0][0], 0, 0, 0);
    acc[0][1] = __builtin_amdgcn_mfma_f32_16x16x32_bf16(a0, b1, acc[0][1], 0, 0, 0);
    acc[1][0] = __builtin_amdgcn_mfma_f32_16x16x32_bf16(a1, b0, acc[1][0], 0, 0, 0);
    acc[1][1] = __builtin_amdgcn_mfma_f32_16x16x32_bf16(a1, b1, acc[1][1], 0, 0, 0);
  }
#pragma unroll
  for (int rh = 0; rh < 2; rh++) {
    int od0 = oW + rh * 16 + quad * 4;
    float b0 = bm[od0], b1 = bm[od0+1], b2 = bm[od0+2], b3 = bm[od0+3];
#pragma unroll
    for (int ch = 0; ch < 2; ch++) {
      int p = pW + ch * 16 + l15;
      size_t base = ((size_t)b * NC + od0) * NP + p;
      out[base]          = acc[rh][ch][0] + b0;
      out[base +     NP] = acc[rh][ch][1] + b1;
      out[base + 2 * NP] = acc[rh][ch][2] + b2;
      out[base + 3 * NP] = acc[rh][ch][3] + b3;
    }
  }
}

extern "C" void kernel_launch(void* const* d_in, const int* in_sizes, int n_in,
                              void* d_out, int out_size, void* d_ws, size_t ws_size,
                              hipStream_t stream) {
  (void)in_sizes; (void)n_in; (void)out_size; (void)ws_size;
  const float* x  = (const float*)d_in[0];
  const float* Wq = (const float*)d_in[1];
  const float* bq = (const float*)d_in[2];
  const float* Wk = (const float*)d_in[3];
  const float* bk = (const float*)d_in[4];
  const float* Wv = (const float*)d_in[5];
  const float* bv = (const float*)d_in[6];
  const float* Wm = (const float*)d_in[7];
  const float* bm = (const float*)d_in[8];
  float* out = (float*)d_out;
  char* ws = (char*)d_ws;

  unsigned short* xt = (unsigned short*)(ws);                              // 4 MB
  unsigned short* Wb = (unsigned short*)(ws + (4u << 20));                 // 512 KB
  unsigned short* qt = (unsigned short*)(ws + (4u << 20) + (512u << 10));  // 4 MB
  unsigned short* kt = (unsigned short*)(ws + (8u << 20) + (512u << 10));  // 4 MB
  unsigned short* vt = (unsigned short*)(ws + (12u << 20) + (512u << 10)); // 4 MB
  unsigned short* at = (unsigned short*)(ws + (16u << 20) + (512u << 10)); // 4 MB

  prep_kernel<<<640, 256, 0, stream>>>(Wq, Wk, Wv, Wm, x, Wb, xt);
  qkv_kernel<<<dim3(64, 8, 3), 256, 0, stream>>>(Wb, bq, bk, bv, xt, qt, kt, vt);
  attn_kernel<<<dim3(16, 64), 256, 0, stream>>>(qt, kt, vt, at);
  mproj_kernel<<<dim3(64, 8), 256, 0, stream>>>(Wb + 3 * 65536, bm, at, out);
}

// Round 2
// 130.955 us; speedup vs baseline: 1.0616x; 1.0375x over previous
//
#include <hip/hip_runtime.h>
#include <cstdint>
#include <cstddef>

// SelfAttention: B=8, C=256, H=W=32, HEADS=8, hd=32, N=HW=1024
// Pipeline (all bf16 MFMA, fp32 accum):
//   prep:  W[4] fp32->bf16 ; x [b,c,p] fp32 -> xt [b,p,c] bf16 (LDS transpose)
//   qkv :  q (pre-scaled by scale*log2e), k -> [b,h,n,d] bf16 ;
//          v -> [b,c,p] bf16 (m-linear)
//   attn:  flash, swapped-operand 32x32x16 form, in-register softmax (T12).
//          R2: 2 n-tiles (64 q rows) per wave sharing K/V fragments -> L2
//          K/V traffic halved (268->134 MB); SPLIT-M x4 (wave w covers
//          m in [w*256,(w+1)*256)); linear 4-way combine through LDS
//          (static softmax -> no rescale), odd-stride pad = conflict-free.
//   mproj: final projection -> d_out fp32
// ws layout: xt 4MB | Wb 512KB | qt 4MB | kt 4MB | vt 4MB | at 4MB  = 20.5 MB

#define NB 8
#define NC 256
#define NP 1024
#define NHD 8
#define HD 32

typedef short bf16x8 __attribute__((ext_vector_type(8)));
typedef float f32x4 __attribute__((ext_vector_type(4)));
typedef float f32x16 __attribute__((ext_vector_type(16)));

// scale * log2(e) : softmax(s/sqrt(32)) computed as 2^(s*SCLLOG)
#define SCLLOG 0.25505654356918f

#define F32X16_ZERO (f32x16){0.f,0.f,0.f,0.f,0.f,0.f,0.f,0.f,0.f,0.f,0.f,0.f,0.f,0.f,0.f,0.f}

// hardware packed fp32->bf16 (RNE): D.lo = bf16(a), D.hi = bf16(b)
__device__ __forceinline__ unsigned cvt_pk_bf16(float a, float b) {
  unsigned r;
  asm("v_cvt_pk_bf16_f32 %0, %1, %2" : "=v"(r) : "v"(a), "v"(b));
  return r;
}
__device__ __forceinline__ unsigned short f2b1(float a) {
  return (unsigned short)cvt_pk_bf16(a, a);
}

// ---------------- prep: weight cvt + x transpose ----------------
__global__ __launch_bounds__(256) void prep_kernel(
    const float* __restrict__ Wq, const float* __restrict__ Wk,
    const float* __restrict__ Wv, const float* __restrict__ Wm,
    const float* __restrict__ x, unsigned short* __restrict__ Wb,
    unsigned short* __restrict__ xt) {
  __shared__ float sx[64][65];
  int bx = blockIdx.x, tid = threadIdx.x;
  if (bx < 128) {
    int idx = (bx * 256 + tid) * 8;
    const float* src; int off;
    if (idx < 65536)       { src = Wq; off = idx; }
    else if (idx < 131072) { src = Wk; off = idx - 65536; }
    else if (idx < 196608) { src = Wv; off = idx - 131072; }
    else                   { src = Wm; off = idx - 196608; }
    float4 lo = *(const float4*)(src + off);
    float4 hi = *(const float4*)(src + off + 4);
    union { unsigned u[4]; bf16x8 v; } o;
    o.u[0] = cvt_pk_bf16(lo.x, lo.y); o.u[1] = cvt_pk_bf16(lo.z, lo.w);
    o.u[2] = cvt_pk_bf16(hi.x, hi.y); o.u[3] = cvt_pk_bf16(hi.z, hi.w);
    *(bf16x8*)(Wb + idx) = o.v;
  } else {
    // transpose one 64c x 64p tile: x[b,c,p] fp32 -> xt[b,p,c] bf16
    int bi = bx - 128;
    int b = bi >> 6, rest = bi & 63;
    int ct = (rest & 3) * 64, pt = (rest >> 2) * 64;
    const float* xb = x + ((size_t)(b * NC + ct)) * NP + pt;
    int pr = (tid & 15) * 4, cr = tid >> 4;
#pragma unroll
    for (int i = 0; i < 4; i++) {
      float4 v = *(const float4*)(xb + (size_t)(cr + i * 16) * NP + pr);
      sx[cr + i*16][pr]   = v.x; sx[cr + i*16][pr+1] = v.y;
      sx[cr + i*16][pr+2] = v.z; sx[cr + i*16][pr+3] = v.w;
    }
    __syncthreads();
    int pl = tid >> 3, cc = (tid & 7) * 8;
#pragma unroll
    for (int j = 0; j < 2; j++) {
      int p = pl + j * 32;
      union { unsigned u[4]; bf16x8 v; } o;
#pragma unroll
      for (int u = 0; u < 4; u++)
        o.u[u] = cvt_pk_bf16(sx[cc + 2*u][p], sx[cc + 2*u + 1][p]);
      *(bf16x8*)(xt + ((size_t)b * NP + pt + p) * NC + ct + cc) = o.v;
    }
  }
}

// ---------------- QKV projection GEMM ----------------
__global__ __launch_bounds__(256) void qkv_kernel(
    const unsigned short* __restrict__ Wb,
    const float* __restrict__ bq, const float* __restrict__ bk,
    const float* __restrict__ bv,
    const unsigned short* __restrict__ xt,
    unsigned short* __restrict__ qt, unsigned short* __restrict__ kt,
    unsigned short* __restrict__ vt) {
  int proj = blockIdx.z, b = blockIdx.y, bx = blockIdx.x;
  int ot = (bx & 3) * 64, pt = (bx >> 2) * 64;
  int tid = threadIdx.x, wave = tid >> 6, lane = tid & 63;
  int l15 = lane & 15, quad = lane >> 4;
  int oW = ot + (wave & 1) * 32, pW = pt + (wave >> 1) * 32;
  const unsigned short* W = Wb + (size_t)proj * 65536;
  const float* bias = (proj == 0) ? bq : (proj == 1) ? bk : bv;
  // q pre-scaled by scale*log2e so attn's softmax is a bare exp2
  float sc = (proj == 0) ? SCLLOG : 1.0f;
  const unsigned short* A0 = W + (size_t)(oW + l15) * NC + quad * 8;
  const unsigned short* B0 = xt + ((size_t)b * NP + pW + l15) * NC + quad * 8;
  f32x4 acc[2][2];
#pragma unroll
  for (int i = 0; i < 2; i++)
#pragma unroll
    for (int j = 0; j < 2; j++) acc[i][j] = (f32x4){0.f, 0.f, 0.f, 0.f};
#pragma unroll
  for (int c0 = 0; c0 < NC; c0 += 32) {
    bf16x8 a0 = *(const bf16x8*)(A0 + c0);
    bf16x8 a1 = *(const bf16x8*)(A0 + 16 * NC + c0);
    bf16x8 b0 = *(const bf16x8*)(B0 + c0);
    bf16x8 b1 = *(const bf16x8*)(B0 + 16 * NC + c0);
    acc[0][0] = __builtin_amdgcn_mfma_f32_16x16x32_bf16(a0, b0, acc[0][0], 0, 0, 0);
    acc[0][1] = __builtin_amdgcn_mfma_f32_16x16x32_bf16(a0, b1, acc[0][1], 0, 0, 0);
    acc[1][0] = __builtin_amdgcn_mfma_f32_16x16x32_bf16(a1, b0, acc[1][0], 0, 0, 0);
    acc[1][1] = __builtin_amdgcn_mfma_f32_16x16x32_bf16(a1, b1, acc[1][1], 0, 0, 0);
  }
  unsigned short* qk = (proj == 0) ? qt : kt;
#pragma unroll
  for (int rh = 0; rh < 2; rh++) {
    int od0 = oW + rh * 16 + quad * 4;             // 4 consecutive o rows
    float b0 = bias[od0], b1 = bias[od0+1], b2 = bias[od0+2], b3 = bias[od0+3];
#pragma unroll
    for (int ch = 0; ch < 2; ch++) {
      float v0 = acc[rh][ch][0] + b0, v1 = acc[rh][ch][1] + b1;
      float v2 = acc[rh][ch][2] + b2, v3 = acc[rh][ch][3] + b3;
      int p = pW + ch * 16 + l15;
      if (proj < 2) {
        int h2 = od0 >> 5, d0 = od0 & 31;
        uint2 pk;
        pk.x = cvt_pk_bf16(v0 * sc, v1 * sc);
        pk.y = cvt_pk_bf16(v2 * sc, v3 * sc);
        size_t idx = ((size_t)(b * NHD + h2) * NP + p) * HD + d0;
        *(uint2*)(qk + idx) = pk;
      } else {
        // v -> [b, c=o, p] bf16, m-linear (matches PV B-operand k=hi*8+j)
        size_t base = ((size_t)b * NC + od0) * NP + p;
        vt[base]          = f2b1(v0);
        vt[base +     NP] = f2b1(v1);
        vt[base + 2 * NP] = f2b1(v2);
        vt[base + 3 * NP] = f2b1(v3);
      }
    }
  }
}

// ---------------- flash attention (swapped 32x32, 2 n-tiles/wave, split-m x4) --
// grid (16, 64); block = 256 threads = 4 waves. Block owns 64 q rows
// (n0 = bx*64, tiles A = n0..n0+31, B = n0+32..n0+63). Wave w covers
// m in [w*256, (w+1)*256), 8 tiles of 32; K/V fragments shared by both
// n-tiles (halves L2 traffic vs 1 n-tile/wave).
// Per tile: S^T = mfma_32x32x16(K,Q) x2 per n-tile -> col = n = lane&31,
//   row m = (r&3)+8*(r>>2)+4*hi (crow). p = 2^s in-register (scale folded
//   into Q, exact after 1/l). P->bf16 A-operand: 8 cvt_pk + 4
//   v_permlane32_swap_b32 per n-tile (T12, verified R1).
// Combine: linear (no max): waves 1-3 dump (O,l) to LDS (stride 35 floats,
// odd -> bank-conflict-free), one __syncthreads, wave 0 adds and stores.
__global__ __launch_bounds__(256, 3) void attn_kernel(
    const unsigned short* __restrict__ qt, const unsigned short* __restrict__ kt,
    const unsigned short* __restrict__ vt, unsigned short* __restrict__ at) {
  int tid = threadIdx.x, wave = tid >> 6, lane = tid & 63;
  int l31 = lane & 31, hi = lane >> 5;
  int bh = blockIdx.y, b = bh >> 3, h = bh & 7;
  int n0 = blockIdx.x * 64;

  __shared__ float Comb[3][64][35];   // [wave-1][lane][32 O + 2 l + pad]
  __shared__ float Linv[2][32];       // [tile][n-in-tile] broadcast of 1/l

  // Q fragments (B-operand): col = n = lane&31, k = d = hi*8+j
  const unsigned short* qpa = qt + ((size_t)bh * NP + n0 + l31) * HD + hi * 8;
  bf16x8 qa0 = *(const bf16x8*)(qpa);
  bf16x8 qa1 = *(const bf16x8*)(qpa + 16);
  bf16x8 qb0 = *(const bf16x8*)(qpa + 32 * HD);
  bf16x8 qb1 = *(const bf16x8*)(qpa + 32 * HD + 16);

  // K rows (A-operand): row = m, k = d = hi*8+j
  const unsigned short* kp = kt + ((size_t)bh * NP + l31) * HD + hi * 8;
  // V (B-operand): col = d = lane&31, k = m = hi*8+j (m-linear layout)
  const unsigned short* vp = vt + ((size_t)(b * NC + h * HD + l31)) * NP + hi * 8;

  f32x16 oa = F32X16_ZERO, ob = F32X16_ZERO;
  f32x4 la = (f32x4){0.f, 0.f, 0.f, 0.f}, lb = (f32x4){0.f, 0.f, 0.f, 0.f};

  int mbase = wave * 256;
  bf16x8 kf0 = *(const bf16x8*)(kp + (size_t)mbase * HD);
  bf16x8 kf1 = *(const bf16x8*)(kp + (size_t)mbase * HD + 16);
  bf16x8 vf0 = *(const bf16x8*)(vp + mbase);
  bf16x8 vf1 = *(const bf16x8*)(vp + mbase + 16);

  for (int m0 = mbase; m0 < mbase + 256; m0 += 32) {
    // prefetch next tile (tail over-read stays inside ws buffers)
    bf16x8 nk0 = *(const bf16x8*)(kp + (size_t)(m0 + 32) * HD);
    bf16x8 nk1 = *(const bf16x8*)(kp + (size_t)(m0 + 32) * HD + 16);
    bf16x8 nv0 = *(const bf16x8*)(vp + m0 + 32);
    bf16x8 nv1 = *(const bf16x8*)(vp + m0 + 48);
    // S^T for both n-tiles off the same K fragments
    f32x16 sa = __builtin_amdgcn_mfma_f32_32x32x16_bf16(kf0, qa0, F32X16_ZERO, 0, 0, 0);
    f32x16 sb = __builtin_amdgcn_mfma_f32_32x32x16_bf16(kf0, qb0, F32X16_ZERO, 0, 0, 0);
    sa = __builtin_amdgcn_mfma_f32_32x32x16_bf16(kf1, qa1, sa, 0, 0, 0);
    sb = __builtin_amdgcn_mfma_f32_32x32x16_bf16(kf1, qb1, sb, 0, 0, 0);
    // p = 2^s (scale folded into Q; exact softmax after 1/l, no max needed)
    float pa[16], pb[16];
#pragma unroll
    for (int r = 0; r < 16; r++) pa[r] = __builtin_amdgcn_exp2f(sa[r]);
#pragma unroll
    for (int r = 0; r < 16; r++) pb[r] = __builtin_amdgcn_exp2f(sb[r]);
#pragma unroll
    for (int r = 0; r < 16; r++) { la[r & 3] += pa[r]; lb[r & 3] += pb[r]; }
    // pack P rows to bf16 A-fragments (T12: cvt_pk + permlane32_swap)
    unsigned a0 = cvt_pk_bf16(pa[0],  pa[1]),  a1 = cvt_pk_bf16(pa[2],  pa[3]);
    unsigned a2 = cvt_pk_bf16(pa[4],  pa[5]),  a3 = cvt_pk_bf16(pa[6],  pa[7]);
    unsigned a4 = cvt_pk_bf16(pa[8],  pa[9]),  a5 = cvt_pk_bf16(pa[10], pa[11]);
    unsigned a6 = cvt_pk_bf16(pa[12], pa[13]), a7 = cvt_pk_bf16(pa[14], pa[15]);
    asm("v_permlane32_swap_b32 %0, %1" : "+v"(a0), "+v"(a2));
    asm("v_permlane32_swap_b32 %0, %1" : "+v"(a1), "+v"(a3));
    asm("v_permlane32_swap_b32 %0, %1" : "+v"(a4), "+v"(a6));
    asm("v_permlane32_swap_b32 %0, %1" : "+v"(a5), "+v"(a7));
    unsigned b0 = cvt_pk_bf16(pb[0],  pb[1]),  b1 = cvt_pk_bf16(pb[2],  pb[3]);
    unsigned b2 = cvt_pk_bf16(pb[4],  pb[5]),  b3 = cvt_pk_bf16(pb[6],  pb[7]);
    unsigned b4 = cvt_pk_bf16(pb[8],  pb[9]),  b5 = cvt_pk_bf16(pb[10], pb[11]);
    unsigned b6 = cvt_pk_bf16(pb[12], pb[13]), b7 = cvt_pk_bf16(pb[14], pb[15]);
    asm("v_permlane32_swap_b32 %0, %1" : "+v"(b0), "+v"(b2));
    asm("v_permlane32_swap_b32 %0, %1" : "+v"(b1), "+v"(b3));
    asm("v_permlane32_swap_b32 %0, %1" : "+v"(b4), "+v"(b6));
    asm("v_permlane32_swap_b32 %0, %1" : "+v"(b5), "+v"(b7));
    union { unsigned u[4]; bf16x8 v; } fa0, fa1, fb0, fb1;
    fa0.u[0] = a0; fa0.u[1] = a1; fa0.u[2] = a2; fa0.u[3] = a3;
    fa1.u[0] = a4; fa1.u[1] = a5; fa1.u[2] = a6; fa1.u[3] = a7;
    fb0.u[0] = b0; fb0.u[1] = b1; fb0.u[2] = b2; fb0.u[3] = b3;
    fb1.u[0] = b4; fb1.u[1] = b5; fb1.u[2] = b6; fb1.u[3] = b7;
    oa = __builtin_amdgcn_mfma_f32_32x32x16_bf16(fa0.v, vf0, oa, 0, 0, 0);
    oa = __builtin_amdgcn_mfma_f32_32x32x16_bf16(fa1.v, vf1, oa, 0, 0, 0);
    ob = __builtin_amdgcn_mfma_f32_32x32x16_bf16(fb0.v, vf0, ob, 0, 0, 0);
    ob = __builtin_amdgcn_mfma_f32_32x32x16_bf16(fb1.v, vf1, ob, 0, 0, 0);
    kf0 = nk0; kf1 = nk1; vf0 = nv0; vf1 = nv1;
  }

  // lane-pair combine of l (lane and lane^32 hold complementary m rows)
  float lsA = (la[0] + la[1]) + (la[2] + la[3]);
  float lsB = (lb[0] + lb[1]) + (lb[2] + lb[3]);
  lsA += __shfl_xor(lsA, 32, 64);
  lsB += __shfl_xor(lsB, 32, 64);

  // ---- combine m-quarters (linear: static softmax -> no rescale) ----
  if (wave) {
    float* Cb = &Comb[wave - 1][lane][0];
#pragma unroll
    for (int r = 0; r < 16; r++) { Cb[r] = oa[r]; Cb[16 + r] = ob[r]; }
    Cb[32] = lsA; Cb[33] = lsB;
  }
  __syncthreads();
  if (wave == 0) {
#pragma unroll
    for (int w = 0; w < 3; w++) {
      const float* Cb = &Comb[w][lane][0];
#pragma unroll
      for (int r = 0; r < 16; r++) { oa[r] += Cb[r]; ob[r] += Cb[16 + r]; }
      lsA += Cb[32]; lsB += Cb[33];
    }
    if (hi == 0) {
      Linv[0][l31] = 1.0f / lsA;    // same-wave RAW: compiler waits
      Linv[1][l31] = 1.0f / lsB;
    }
    // O[n = n0+crow(r,hi), d = l31] -> at[b, n, c = d*8 + h]
    unsigned short* ab = at + (size_t)b * NP * NC + (size_t)(l31 * 8 + h);
#pragma unroll
    for (int r = 0; r < 16; r++) {
      int crow = (r & 3) + 8 * (r >> 2) + 4 * hi;
      ab[(size_t)(n0 + crow) * NC]      = f2b1(oa[r] * Linv[0][crow]);
      ab[(size_t)(n0 + 32 + crow) * NC] = f2b1(ob[r] * Linv[1][crow]);
    }
  }
}

// ---------------- output projection ----------------
__global__ __launch_bounds__(256) void mproj_kernel(
    const unsigned short* __restrict__ Wmb, const float* __restrict__ bm,
    const unsigned short* __restrict__ at, float* __restrict__ out) {
  int b = blockIdx.y, bx = blockIdx.x;
  int ot = (bx & 3) * 64, pt = (bx >> 2) * 64;
  int tid = threadIdx.x, wave = tid >> 6, lane = tid & 63;
  int l15 = lane & 15, quad = lane >> 4;
  int oW = ot + (wave & 1) * 32, pW = pt + (wave >> 1) * 32;
  const unsigned short* A0 = Wmb + (size_t)(oW + l15) * NC + quad * 8;
  const unsigned short* B0 = at + ((size_t)b * NP + pW + l15) * NC + quad * 8;
  f32x4 acc[2][2];
#pragma unroll
  for (int i = 0; i < 2; i++)
#pragma unroll
    for (int j = 0; j < 2; j++) acc[i][j] = (f32x4){0.f, 0.f, 0.f, 0.f};
#pragma unroll
  for (int c0 = 0; c0 < NC; c0 += 32) {
    bf16x8 a0 = *(const bf16x8*)(A0 + c0);
    bf16x8 a1 = *(const bf16x8*)(A0 + 16 * NC + c0);
    bf16x8 b0 = *(const bf16x8*)(B0 + c0);
    bf16x8 b1 = *(const bf16x8*)(B0 + 16 * NC + c0);
    acc[0][0] = __builtin_amdgcn_mfma_f32_16x16x32_bf16(a0, b0, acc[0][0], 0, 0, 0);
    acc[0][1] = __builtin_amdgcn_mfma_f32_16x16x32_bf16(a0, b1, acc[0][1], 0, 0, 0);
    acc[1][0] = __builtin_amdgcn_mfma_f32_16x16x32_bf16(a1, b0, acc[1][0], 0, 0, 0);
    acc[1][1] = __builtin_amdgcn_mfma_f32_16x16x32_bf16(a1, b1, acc[1][1], 0, 0, 0);
  }
#pragma unroll
  for (int rh = 0; rh < 2; rh++) {
    int od0 = oW + rh * 16 + quad * 4;
    float b0 = bm[od0], b1 = bm[od0+1], b2 = bm[od0+2], b3 = bm[od0+3];
#pragma unroll
    for (int ch = 0; ch < 2; ch++) {
      int p = pW + ch * 16 + l15;
      size_t base = ((size_t)b * NC + od0) * NP + p;
      out[base]          = acc[rh][ch][0] + b0;
      out[base +     NP] = acc[rh][ch][1] + b1;
      out[base + 2 * NP] = acc[rh][ch][2] + b2;
      out[base + 3 * NP] = acc[rh][ch][3] + b3;
    }
  }
}

extern "C" void kernel_launch(void* const* d_in, const int* in_sizes, int n_in,
                              void* d_out, int out_size, void* d_ws, size_t ws_size,
                              hipStream_t stream) {
  (void)in_sizes; (void)n_in; (void)out_size; (void)ws_size;
  const float* x  = (const float*)d_in[0];
  const float* Wq = (const float*)d_in[1];
  const float* bq = (const float*)d_in[2];
  const float* Wk = (const float*)d_in[3];
  const float* bk = (const float*)d_in[4];
  const float* Wv = (const float*)d_in[5];
  const float* bv = (const float*)d_in[6];
  const float* Wm = (const float*)d_in[7];
  const float* bm = (const float*)d_in[8];
  float* out = (float*)d_out;
  char* ws = (char*)d_ws;

  unsigned short* xt = (unsigned short*)(ws);                              // 4 MB
  unsigned short* Wb = (unsigned short*)(ws + (4u << 20));                 // 512 KB
  unsigned short* qt = (unsigned short*)(ws + (4u << 20) + (512u << 10));  // 4 MB
  unsigned short* kt = (unsigned short*)(ws + (8u << 20) + (512u << 10));  // 4 MB
  unsigned short* vt = (unsigned short*)(ws + (12u << 20) + (512u << 10)); // 4 MB
  unsigned short* at = (unsigned short*)(ws + (16u << 20) + (512u << 10)); // 4 MB

  prep_kernel<<<640, 256, 0, stream>>>(Wq, Wk, Wv, Wm, x, Wb, xt);
  qkv_kernel<<<dim3(64, 8, 3), 256, 0, stream>>>(Wb, bq, bk, bv, xt, qt, kt, vt);
  attn_kernel<<<dim3(16, 64), 256, 0, stream>>>(qt, kt, vt, at);
  mproj_kernel<<<dim3(64, 8), 256, 0, stream>>>(Wb + 3 * 65536, bm, at, out);
}

// Round 4
// 124.015 us; speedup vs baseline: 1.1210x; 1.0560x over previous
//
#include <hip/hip_runtime.h>
#include <cstdint>
#include <cstddef>

// SelfAttention: B=8, C=256, H=W=32, HEADS=8, hd=32, N=HW=1024
// Pipeline (all bf16 MFMA, fp32 accum):
//   prep:  W[4] fp32->bf16 ; x [b,c,p] fp32 -> xt [b,p,c] bf16 (LDS transpose)
//   qkv :  R4: 3 projections fused per block (xt B-fragments read once,
//          reused for q,k,v) -> L2 98->65MB. q pre-scaled by scale*log2e.
//          Per-proj MFMA order unchanged -> bit-identical q/k/v vs R2.
//   attn:  R2-VERBATIM (passing): flash, swapped-operand 32x32x16,
//          in-register softmax (T12), 2 n-tiles (64 q rows) per wave
//          sharing K/V fragments; SPLIT-M x4 (wave w: m [w*256,+256));
//          linear 4-way combine through LDS, odd stride 35 conflict-free.
//          (R3's 4-n-tile variant FAILED correctness; reverted.)
//   mproj: final projection -> d_out fp32
// ws layout: xt 4MB | Wb 512KB | qt 4MB | kt 4MB | vt 4MB | at 4MB  = 20.5 MB

#define NB 8
#define NC 256
#define NP 1024
#define NHD 8
#define HD 32

typedef short bf16x8 __attribute__((ext_vector_type(8)));
typedef float f32x4 __attribute__((ext_vector_type(4)));
typedef float f32x16 __attribute__((ext_vector_type(16)));

// scale * log2(e) : softmax(s/sqrt(32)) computed as 2^(s*SCLLOG)
#define SCLLOG 0.25505654356918f

#define F32X16_ZERO (f32x16){0.f,0.f,0.f,0.f,0.f,0.f,0.f,0.f,0.f,0.f,0.f,0.f,0.f,0.f,0.f,0.f}

// hardware packed fp32->bf16 (RNE): D.lo = bf16(a), D.hi = bf16(b)
__device__ __forceinline__ unsigned cvt_pk_bf16(float a, float b) {
  unsigned r;
  asm("v_cvt_pk_bf16_f32 %0, %1, %2" : "=v"(r) : "v"(a), "v"(b));
  return r;
}
__device__ __forceinline__ unsigned short f2b1(float a) {
  return (unsigned short)cvt_pk_bf16(a, a);
}

// ---------------- prep: weight cvt + x transpose ----------------
__global__ __launch_bounds__(256) void prep_kernel(
    const float* __restrict__ Wq, const float* __restrict__ Wk,
    const float* __restrict__ Wv, const float* __restrict__ Wm,
    const float* __restrict__ x, unsigned short* __restrict__ Wb,
    unsigned short* __restrict__ xt) {
  __shared__ float sx[64][65];
  int bx = blockIdx.x, tid = threadIdx.x;
  if (bx < 128) {
    int idx = (bx * 256 + tid) * 8;
    const float* src; int off;
    if (idx < 65536)       { src = Wq; off = idx; }
    else if (idx < 131072) { src = Wk; off = idx - 65536; }
    else if (idx < 196608) { src = Wv; off = idx - 131072; }
    else                   { src = Wm; off = idx - 196608; }
    float4 lo = *(const float4*)(src + off);
    float4 hi = *(const float4*)(src + off + 4);
    union { unsigned u[4]; bf16x8 v; } o;
    o.u[0] = cvt_pk_bf16(lo.x, lo.y); o.u[1] = cvt_pk_bf16(lo.z, lo.w);
    o.u[2] = cvt_pk_bf16(hi.x, hi.y); o.u[3] = cvt_pk_bf16(hi.z, hi.w);
    *(bf16x8*)(Wb + idx) = o.v;
  } else {
    // transpose one 64c x 64p tile: x[b,c,p] fp32 -> xt[b,p,c] bf16
    int bi = bx - 128;
    int b = bi >> 6, rest = bi & 63;
    int ct = (rest & 3) * 64, pt = (rest >> 2) * 64;
    const float* xb = x + ((size_t)(b * NC + ct)) * NP + pt;
    int pr = (tid & 15) * 4, cr = tid >> 4;
#pragma unroll
    for (int i = 0; i < 4; i++) {
      float4 v = *(const float4*)(xb + (size_t)(cr + i * 16) * NP + pr);
      sx[cr + i*16][pr]   = v.x; sx[cr + i*16][pr+1] = v.y;
      sx[cr + i*16][pr+2] = v.z; sx[cr + i*16][pr+3] = v.w;
    }
    __syncthreads();
    int pl = tid >> 3, cc = (tid & 7) * 8;
#pragma unroll
    for (int j = 0; j < 2; j++) {
      int p = pl + j * 32;
      union { unsigned u[4]; bf16x8 v; } o;
#pragma unroll
      for (int u = 0; u < 4; u++)
        o.u[u] = cvt_pk_bf16(sx[cc + 2*u][p], sx[cc + 2*u + 1][p]);
      *(bf16x8*)(xt + ((size_t)b * NP + pt + p) * NC + ct + cc) = o.v;
    }
  }
}

// ---------------- QKV projection GEMM (3 projections fused) ----------------
__global__ __launch_bounds__(256) void qkv_kernel(
    const unsigned short* __restrict__ Wb,
    const float* __restrict__ bq, const float* __restrict__ bk,
    const float* __restrict__ bv,
    const unsigned short* __restrict__ xt,
    unsigned short* __restrict__ qt, unsigned short* __restrict__ kt,
    unsigned short* __restrict__ vt) {
  int b = blockIdx.y, bx = blockIdx.x;
  int ot = (bx & 3) * 64, pt = (bx >> 2) * 64;
  int tid = threadIdx.x, wave = tid >> 6, lane = tid & 63;
  int l15 = lane & 15, quad = lane >> 4;
  int oW = ot + (wave & 1) * 32, pW = pt + (wave >> 1) * 32;
  const unsigned short* A0 = Wb + (size_t)(oW + l15) * NC + quad * 8;
  const unsigned short* B0 = xt + ((size_t)b * NP + pW + l15) * NC + quad * 8;
  f32x4 acc[3][2][2];
#pragma unroll
  for (int pj = 0; pj < 3; pj++)
#pragma unroll
    for (int i = 0; i < 2; i++)
#pragma unroll
      for (int j = 0; j < 2; j++) acc[pj][i][j] = (f32x4){0.f, 0.f, 0.f, 0.f};
#pragma unroll
  for (int c0 = 0; c0 < NC; c0 += 32) {
    // xt B-fragments loaded once, reused by all 3 projections
    bf16x8 b0 = *(const bf16x8*)(B0 + c0);
    bf16x8 b1 = *(const bf16x8*)(B0 + 16 * NC + c0);
#pragma unroll
    for (int pj = 0; pj < 3; pj++) {
      bf16x8 a0 = *(const bf16x8*)(A0 + pj * 65536 + c0);
      bf16x8 a1 = *(const bf16x8*)(A0 + pj * 65536 + 16 * NC + c0);
      acc[pj][0][0] = __builtin_amdgcn_mfma_f32_16x16x32_bf16(a0, b0, acc[pj][0][0], 0, 0, 0);
      acc[pj][0][1] = __builtin_amdgcn_mfma_f32_16x16x32_bf16(a0, b1, acc[pj][0][1], 0, 0, 0);
      acc[pj][1][0] = __builtin_amdgcn_mfma_f32_16x16x32_bf16(a1, b0, acc[pj][1][0], 0, 0, 0);
      acc[pj][1][1] = __builtin_amdgcn_mfma_f32_16x16x32_bf16(a1, b1, acc[pj][1][1], 0, 0, 0);
    }
  }
#pragma unroll
  for (int pj = 0; pj < 3; pj++) {
    const float* bias = (pj == 0) ? bq : (pj == 1) ? bk : bv;
    // q pre-scaled by scale*log2e so attn's softmax is a bare exp2
    float sc = (pj == 0) ? SCLLOG : 1.0f;
    unsigned short* qk = (pj == 0) ? qt : kt;
#pragma unroll
    for (int rh = 0; rh < 2; rh++) {
      int od0 = oW + rh * 16 + quad * 4;           // 4 consecutive o rows
      float b0 = bias[od0], b1 = bias[od0+1], b2 = bias[od0+2], b3 = bias[od0+3];
#pragma unroll
      for (int ch = 0; ch < 2; ch++) {
        float v0 = acc[pj][rh][ch][0] + b0, v1 = acc[pj][rh][ch][1] + b1;
        float v2 = acc[pj][rh][ch][2] + b2, v3 = acc[pj][rh][ch][3] + b3;
        int p = pW + ch * 16 + l15;
        if (pj < 2) {
          int h2 = od0 >> 5, d0 = od0 & 31;
          uint2 pk;
          pk.x = cvt_pk_bf16(v0 * sc, v1 * sc);
          pk.y = cvt_pk_bf16(v2 * sc, v3 * sc);
          size_t idx = ((size_t)(b * NHD + h2) * NP + p) * HD + d0;
          *(uint2*)(qk + idx) = pk;
        } else {
          // v -> [b, c=o, p] bf16, m-linear (matches PV B-operand k=hi*8+j)
          size_t base = ((size_t)b * NC + od0) * NP + p;
          vt[base]          = f2b1(v0);
          vt[base +     NP] = f2b1(v1);
          vt[base + 2 * NP] = f2b1(v2);
          vt[base + 3 * NP] = f2b1(v3);
        }
      }
    }
  }
}

// ---------------- flash attention (swapped 32x32, 2 n-tiles/wave, split-m x4) --
// R2-VERBATIM (passing at 130.95us / absmax 0.00293).
// grid (16, 64); block = 256 threads = 4 waves. Block owns 64 q rows
// (n0 = bx*64, tiles A = n0..n0+31, B = n0+32..n0+63). Wave w covers
// m in [w*256, (w+1)*256), 8 tiles of 32; K/V fragments shared by both
// n-tiles.
// Per tile: S^T = mfma_32x32x16(K,Q) x2 per n-tile -> col = n = lane&31,
//   row m = (r&3)+8*(r>>2)+4*hi (crow). p = 2^s in-register (scale folded
//   into Q, exact after 1/l). P->bf16 A-operand: 8 cvt_pk + 4
//   v_permlane32_swap_b32 (T12, verified R1/R2).
// Combine: linear (no max): waves 1-3 dump (O,l) to LDS (stride 35 floats,
// odd -> bank-conflict-free), one __syncthreads, wave 0 adds and stores.
__global__ __launch_bounds__(256, 3) void attn_kernel(
    const unsigned short* __restrict__ qt, const unsigned short* __restrict__ kt,
    const unsigned short* __restrict__ vt, unsigned short* __restrict__ at) {
  int tid = threadIdx.x, wave = tid >> 6, lane = tid & 63;
  int l31 = lane & 31, hi = lane >> 5;
  int bh = blockIdx.y, b = bh >> 3, h = bh & 7;
  int n0 = blockIdx.x * 64;

  __shared__ float Comb[3][64][35];   // [wave-1][lane][32 O + 2 l + pad]
  __shared__ float Linv[2][32];       // [tile][n-in-tile] broadcast of 1/l

  // Q fragments (B-operand): col = n = lane&31, k = d = hi*8+j
  const unsigned short* qpa = qt + ((size_t)bh * NP + n0 + l31) * HD + hi * 8;
  bf16x8 qa0 = *(const bf16x8*)(qpa);
  bf16x8 qa1 = *(const bf16x8*)(qpa + 16);
  bf16x8 qb0 = *(const bf16x8*)(qpa + 32 * HD);
  bf16x8 qb1 = *(const bf16x8*)(qpa + 32 * HD + 16);

  // K rows (A-operand): row = m, k = d = hi*8+j
  const unsigned short* kp = kt + ((size_t)bh * NP + l31) * HD + hi * 8;
  // V (B-operand): col = d = lane&31, k = m = hi*8+j (m-linear layout)
  const unsigned short* vp = vt + ((size_t)(b * NC + h * HD + l31)) * NP + hi * 8;

  f32x16 oa = F32X16_ZERO, ob = F32X16_ZERO;
  f32x4 la = (f32x4){0.f, 0.f, 0.f, 0.f}, lb = (f32x4){0.f, 0.f, 0.f, 0.f};

  int mbase = wave * 256;
  bf16x8 kf0 = *(const bf16x8*)(kp + (size_t)mbase * HD);
  bf16x8 kf1 = *(const bf16x8*)(kp + (size_t)mbase * HD + 16);
  bf16x8 vf0 = *(const bf16x8*)(vp + mbase);
  bf16x8 vf1 = *(const bf16x8*)(vp + mbase + 16);

  for (int m0 = mbase; m0 < mbase + 256; m0 += 32) {
    // prefetch next tile (tail over-read stays inside ws buffers)
    bf16x8 nk0 = *(const bf16x8*)(kp + (size_t)(m0 + 32) * HD);
    bf16x8 nk1 = *(const bf16x8*)(kp + (size_t)(m0 + 32) * HD + 16);
    bf16x8 nv0 = *(const bf16x8*)(vp + m0 + 32);
    bf16x8 nv1 = *(const bf16x8*)(vp + m0 + 48);
    // S^T for both n-tiles off the same K fragments
    f32x16 sa = __builtin_amdgcn_mfma_f32_32x32x16_bf16(kf0, qa0, F32X16_ZERO, 0, 0, 0);
    f32x16 sb = __builtin_amdgcn_mfma_f32_32x32x16_bf16(kf0, qb0, F32X16_ZERO, 0, 0, 0);
    sa = __builtin_amdgcn_mfma_f32_32x32x16_bf16(kf1, qa1, sa, 0, 0, 0);
    sb = __builtin_amdgcn_mfma_f32_32x32x16_bf16(kf1, qb1, sb, 0, 0, 0);
    // p = 2^s (scale folded into Q; exact softmax after 1/l, no max needed)
    float pa[16], pb[16];
#pragma unroll
    for (int r = 0; r < 16; r++) pa[r] = __builtin_amdgcn_exp2f(sa[r]);
#pragma unroll
    for (int r = 0; r < 16; r++) pb[r] = __builtin_amdgcn_exp2f(sb[r]);
#pragma unroll
    for (int r = 0; r < 16; r++) { la[r & 3] += pa[r]; lb[r & 3] += pb[r]; }
    // pack P rows to bf16 A-fragments (T12: cvt_pk + permlane32_swap)
    unsigned a0 = cvt_pk_bf16(pa[0],  pa[1]),  a1 = cvt_pk_bf16(pa[2],  pa[3]);
    unsigned a2 = cvt_pk_bf16(pa[4],  pa[5]),  a3 = cvt_pk_bf16(pa[6],  pa[7]);
    unsigned a4 = cvt_pk_bf16(pa[8],  pa[9]),  a5 = cvt_pk_bf16(pa[10], pa[11]);
    unsigned a6 = cvt_pk_bf16(pa[12], pa[13]), a7 = cvt_pk_bf16(pa[14], pa[15]);
    asm("v_permlane32_swap_b32 %0, %1" : "+v"(a0), "+v"(a2));
    asm("v_permlane32_swap_b32 %0, %1" : "+v"(a1), "+v"(a3));
    asm("v_permlane32_swap_b32 %0, %1" : "+v"(a4), "+v"(a6));
    asm("v_permlane32_swap_b32 %0, %1" : "+v"(a5), "+v"(a7));
    unsigned b0 = cvt_pk_bf16(pb[0],  pb[1]),  b1 = cvt_pk_bf16(pb[2],  pb[3]);
    unsigned b2 = cvt_pk_bf16(pb[4],  pb[5]),  b3 = cvt_pk_bf16(pb[6],  pb[7]);
    unsigned b4 = cvt_pk_bf16(pb[8],  pb[9]),  b5 = cvt_pk_bf16(pb[10], pb[11]);
    unsigned b6 = cvt_pk_bf16(pb[12], pb[13]), b7 = cvt_pk_bf16(pb[14], pb[15]);
    asm("v_permlane32_swap_b32 %0, %1" : "+v"(b0), "+v"(b2));
    asm("v_permlane32_swap_b32 %0, %1" : "+v"(b1), "+v"(b3));
    asm("v_permlane32_swap_b32 %0, %1" : "+v"(b4), "+v"(b6));
    asm("v_permlane32_swap_b32 %0, %1" : "+v"(b5), "+v"(b7));
    union { unsigned u[4]; bf16x8 v; } fa0, fa1, fb0, fb1;
    fa0.u[0] = a0; fa0.u[1] = a1; fa0.u[2] = a2; fa0.u[3] = a3;
    fa1.u[0] = a4; fa1.u[1] = a5; fa1.u[2] = a6; fa1.u[3] = a7;
    fb0.u[0] = b0; fb0.u[1] = b1; fb0.u[2] = b2; fb0.u[3] = b3;
    fb1.u[0] = b4; fb1.u[1] = b5; fb1.u[2] = b6; fb1.u[3] = b7;
    oa = __builtin_amdgcn_mfma_f32_32x32x16_bf16(fa0.v, vf0, oa, 0, 0, 0);
    oa = __builtin_amdgcn_mfma_f32_32x32x16_bf16(fa1.v, vf1, oa, 0, 0, 0);
    ob = __builtin_amdgcn_mfma_f32_32x32x16_bf16(fb0.v, vf0, ob, 0, 0, 0);
    ob = __builtin_amdgcn_mfma_f32_32x32x16_bf16(fb1.v, vf1, ob, 0, 0, 0);
    kf0 = nk0; kf1 = nk1; vf0 = nv0; vf1 = nv1;
  }

  // lane-pair combine of l (lane and lane^32 hold complementary m rows)
  float lsA = (la[0] + la[1]) + (la[2] + la[3]);
  float lsB = (lb[0] + lb[1]) + (lb[2] + lb[3]);
  lsA += __shfl_xor(lsA, 32, 64);
  lsB += __shfl_xor(lsB, 32, 64);

  // ---- combine m-quarters (linear: static softmax -> no rescale) ----
  if (wave) {
    float* Cb = &Comb[wave - 1][lane][0];
#pragma unroll
    for (int r = 0; r < 16; r++) { Cb[r] = oa[r]; Cb[16 + r] = ob[r]; }
    Cb[32] = lsA; Cb[33] = lsB;
  }
  __syncthreads();
  if (wave == 0) {
#pragma unroll
    for (int w = 0; w < 3; w++) {
      const float* Cb = &Comb[w][lane][0];
#pragma unroll
      for (int r = 0; r < 16; r++) { oa[r] += Cb[r]; ob[r] += Cb[16 + r]; }
      lsA += Cb[32]; lsB += Cb[33];
    }
    if (hi == 0) {
      Linv[0][l31] = 1.0f / lsA;    // same-wave RAW: compiler waits
      Linv[1][l31] = 1.0f / lsB;
    }
    // O[n = n0+crow(r,hi), d = l31] -> at[b, n, c = d*8 + h]
    unsigned short* ab = at + (size_t)b * NP * NC + (size_t)(l31 * 8 + h);
#pragma unroll
    for (int r = 0; r < 16; r++) {
      int crow = (r & 3) + 8 * (r >> 2) + 4 * hi;
      ab[(size_t)(n0 + crow) * NC]      = f2b1(oa[r] * Linv[0][crow]);
      ab[(size_t)(n0 + 32 + crow) * NC] = f2b1(ob[r] * Linv[1][crow]);
    }
  }
}

// ---------------- output projection ----------------
__global__ __launch_bounds__(256) void mproj_kernel(
    const unsigned short* __restrict__ Wmb, const float* __restrict__ bm,
    const unsigned short* __restrict__ at, float* __restrict__ out) {
  int b = blockIdx.y, bx = blockIdx.x;
  int ot = (bx & 3) * 64, pt = (bx >> 2) * 64;
  int tid = threadIdx.x, wave = tid >> 6, lane = tid & 63;
  int l15 = lane & 15, quad = lane >> 4;
  int oW = ot + (wave & 1) * 32, pW = pt + (wave >> 1) * 32;
  const unsigned short* A0 = Wmb + (size_t)(oW + l15) * NC + quad * 8;
  const unsigned short* B0 = at + ((size_t)b * NP + pW + l15) * NC + quad * 8;
  f32x4 acc[2][2];
#pragma unroll
  for (int i = 0; i < 2; i++)
#pragma unroll
    for (int j = 0; j < 2; j++) acc[i][j] = (f32x4){0.f, 0.f, 0.f, 0.f};
#pragma unroll
  for (int c0 = 0; c0 < NC; c0 += 32) {
    bf16x8 a0 = *(const bf16x8*)(A0 + c0);
    bf16x8 a1 = *(const bf16x8*)(A0 + 16 * NC + c0);
    bf16x8 b0 = *(const bf16x8*)(B0 + c0);
    bf16x8 b1 = *(const bf16x8*)(B0 + 16 * NC + c0);
    acc[0][0] = __builtin_amdgcn_mfma_f32_16x16x32_bf16(a0, b0, acc[0][0], 0, 0, 0);
    acc[0][1] = __builtin_amdgcn_mfma_f32_16x16x32_bf16(a0, b1, acc[0][1], 0, 0, 0);
    acc[1][0] = __builtin_amdgcn_mfma_f32_16x16x32_bf16(a1, b0, acc[1][0], 0, 0, 0);
    acc[1][1] = __builtin_amdgcn_mfma_f32_16x16x32_bf16(a1, b1, acc[1][1], 0, 0, 0);
  }
#pragma unroll
  for (int rh = 0; rh < 2; rh++) {
    int od0 = oW + rh * 16 + quad * 4;
    float b0 = bm[od0], b1 = bm[od0+1], b2 = bm[od0+2], b3 = bm[od0+3];
#pragma unroll
    for (int ch = 0; ch < 2; ch++) {
      int p = pW + ch * 16 + l15;
      size_t base = ((size_t)b * NC + od0) * NP + p;
      out[base]          = acc[rh][ch][0] + b0;
      out[base +     NP] = acc[rh][ch][1] + b1;
      out[base + 2 * NP] = acc[rh][ch][2] + b2;
      out[base + 3 * NP] = acc[rh][ch][3] + b3;
    }
  }
}

extern "C" void kernel_launch(void* const* d_in, const int* in_sizes, int n_in,
                              void* d_out, int out_size, void* d_ws, size_t ws_size,
                              hipStream_t stream) {
  (void)in_sizes; (void)n_in; (void)out_size; (void)ws_size;
  const float* x  = (const float*)d_in[0];
  const float* Wq = (const float*)d_in[1];
  const float* bq = (const float*)d_in[2];
  const float* Wk = (const float*)d_in[3];
  const float* bk = (const float*)d_in[4];
  const float* Wv = (const float*)d_in[5];
  const float* bv = (const float*)d_in[6];
  const float* Wm = (const float*)d_in[7];
  const float* bm = (const float*)d_in[8];
  float* out = (float*)d_out;
  char* ws = (char*)d_ws;

  unsigned short* xt = (unsigned short*)(ws);                              // 4 MB
  unsigned short* Wb = (unsigned short*)(ws + (4u << 20));                 // 512 KB
  unsigned short* qt = (unsigned short*)(ws + (4u << 20) + (512u << 10));  // 4 MB
  unsigned short* kt = (unsigned short*)(ws + (8u << 20) + (512u << 10));  // 4 MB
  unsigned short* vt = (unsigned short*)(ws + (12u << 20) + (512u << 10)); // 4 MB
  unsigned short* at = (unsigned short*)(ws + (16u << 20) + (512u << 10)); // 4 MB

  prep_kernel<<<640, 256, 0, stream>>>(Wq, Wk, Wv, Wm, x, Wb, xt);
  qkv_kernel<<<dim3(64, 8), 256, 0, stream>>>(Wb, bq, bk, bv, xt, qt, kt, vt);
  attn_kernel<<<dim3(16, 64), 256, 0, stream>>>(qt, kt, vt, at);
  mproj_kernel<<<dim3(64, 8), 256, 0, stream>>>(Wb + 3 * 65536, bm, at, out);
}

// Round 5
// 123.525 us; speedup vs baseline: 1.1255x; 1.0040x over previous
//
#include <hip/hip_runtime.h>
#include <cstdint>
#include <cstddef>

// SelfAttention: B=8, C=256, H=W=32, HEADS=8, hd=32, N=HW=1024
// Pipeline (all bf16 MFMA, fp32 accum):
//   prep:  W[4] fp32->bf16 ; x [b,c,p] fp32 -> xt [b,p,c] bf16 (LDS transpose)
//   qkv :  3 projections fused per block (xt B-fragments read once,
//          reused for q,k,v). q pre-scaled by scale*log2e. (verified R4)
//   attn:  R5: 4 n-tiles (128 q rows) per wave sharing K/V fragments,
//          NAMED SCALARS ONLY (R3's array/loop form failed; this is the
//          verified R2 2-tile body + verbatim duplicate for tiles c,d).
//          L2 K/V traffic 134->67MB, 2x ILP per wave. SPLIT-M x4.
//          Linear combine through LDS (static softmax -> no rescale),
//          odd stride 69 -> conflict-free.
//   mproj: final projection -> d_out fp32
// ws layout: xt 4MB | Wb 512KB | qt 4MB | kt 4MB | vt 4MB | at 4MB  = 20.5 MB

#define NB 8
#define NC 256
#define NP 1024
#define NHD 8
#define HD 32

typedef short bf16x8 __attribute__((ext_vector_type(8)));
typedef float f32x4 __attribute__((ext_vector_type(4)));
typedef float f32x16 __attribute__((ext_vector_type(16)));

// scale * log2(e) : softmax(s/sqrt(32)) computed as 2^(s*SCLLOG)
#define SCLLOG 0.25505654356918f

#define F32X16_ZERO (f32x16){0.f,0.f,0.f,0.f,0.f,0.f,0.f,0.f,0.f,0.f,0.f,0.f,0.f,0.f,0.f,0.f}

// hardware packed fp32->bf16 (RNE): D.lo = bf16(a), D.hi = bf16(b)
__device__ __forceinline__ unsigned cvt_pk_bf16(float a, float b) {
  unsigned r;
  asm("v_cvt_pk_bf16_f32 %0, %1, %2" : "=v"(r) : "v"(a), "v"(b));
  return r;
}
__device__ __forceinline__ unsigned short f2b1(float a) {
  return (unsigned short)cvt_pk_bf16(a, a);
}

// ---------------- prep: weight cvt + x transpose ----------------
__global__ __launch_bounds__(256) void prep_kernel(
    const float* __restrict__ Wq, const float* __restrict__ Wk,
    const float* __restrict__ Wv, const float* __restrict__ Wm,
    const float* __restrict__ x, unsigned short* __restrict__ Wb,
    unsigned short* __restrict__ xt) {
  __shared__ float sx[64][65];
  int bx = blockIdx.x, tid = threadIdx.x;
  if (bx < 128) {
    int idx = (bx * 256 + tid) * 8;
    const float* src; int off;
    if (idx < 65536)       { src = Wq; off = idx; }
    else if (idx < 131072) { src = Wk; off = idx - 65536; }
    else if (idx < 196608) { src = Wv; off = idx - 131072; }
    else                   { src = Wm; off = idx - 196608; }
    float4 lo = *(const float4*)(src + off);
    float4 hi = *(const float4*)(src + off + 4);
    union { unsigned u[4]; bf16x8 v; } o;
    o.u[0] = cvt_pk_bf16(lo.x, lo.y); o.u[1] = cvt_pk_bf16(lo.z, lo.w);
    o.u[2] = cvt_pk_bf16(hi.x, hi.y); o.u[3] = cvt_pk_bf16(hi.z, hi.w);
    *(bf16x8*)(Wb + idx) = o.v;
  } else {
    // transpose one 64c x 64p tile: x[b,c,p] fp32 -> xt[b,p,c] bf16
    int bi = bx - 128;
    int b = bi >> 6, rest = bi & 63;
    int ct = (rest & 3) * 64, pt = (rest >> 2) * 64;
    const float* xb = x + ((size_t)(b * NC + ct)) * NP + pt;
    int pr = (tid & 15) * 4, cr = tid >> 4;
#pragma unroll
    for (int i = 0; i < 4; i++) {
      float4 v = *(const float4*)(xb + (size_t)(cr + i * 16) * NP + pr);
      sx[cr + i*16][pr]   = v.x; sx[cr + i*16][pr+1] = v.y;
      sx[cr + i*16][pr+2] = v.z; sx[cr + i*16][pr+3] = v.w;
    }
    __syncthreads();
    int pl = tid >> 3, cc = (tid & 7) * 8;
#pragma unroll
    for (int j = 0; j < 2; j++) {
      int p = pl + j * 32;
      union { unsigned u[4]; bf16x8 v; } o;
#pragma unroll
      for (int u = 0; u < 4; u++)
        o.u[u] = cvt_pk_bf16(sx[cc + 2*u][p], sx[cc + 2*u + 1][p]);
      *(bf16x8*)(xt + ((size_t)b * NP + pt + p) * NC + ct + cc) = o.v;
    }
  }
}

// ---------------- QKV projection GEMM (3 projections fused) ----------------
__global__ __launch_bounds__(256) void qkv_kernel(
    const unsigned short* __restrict__ Wb,
    const float* __restrict__ bq, const float* __restrict__ bk,
    const float* __restrict__ bv,
    const unsigned short* __restrict__ xt,
    unsigned short* __restrict__ qt, unsigned short* __restrict__ kt,
    unsigned short* __restrict__ vt) {
  int b = blockIdx.y, bx = blockIdx.x;
  int ot = (bx & 3) * 64, pt = (bx >> 2) * 64;
  int tid = threadIdx.x, wave = tid >> 6, lane = tid & 63;
  int l15 = lane & 15, quad = lane >> 4;
  int oW = ot + (wave & 1) * 32, pW = pt + (wave >> 1) * 32;
  const unsigned short* A0 = Wb + (size_t)(oW + l15) * NC + quad * 8;
  const unsigned short* B0 = xt + ((size_t)b * NP + pW + l15) * NC + quad * 8;
  f32x4 acc[3][2][2];
#pragma unroll
  for (int pj = 0; pj < 3; pj++)
#pragma unroll
    for (int i = 0; i < 2; i++)
#pragma unroll
      for (int j = 0; j < 2; j++) acc[pj][i][j] = (f32x4){0.f, 0.f, 0.f, 0.f};
#pragma unroll
  for (int c0 = 0; c0 < NC; c0 += 32) {
    // xt B-fragments loaded once, reused by all 3 projections
    bf16x8 b0 = *(const bf16x8*)(B0 + c0);
    bf16x8 b1 = *(const bf16x8*)(B0 + 16 * NC + c0);
#pragma unroll
    for (int pj = 0; pj < 3; pj++) {
      bf16x8 a0 = *(const bf16x8*)(A0 + pj * 65536 + c0);
      bf16x8 a1 = *(const bf16x8*)(A0 + pj * 65536 + 16 * NC + c0);
      acc[pj][0][0] = __builtin_amdgcn_mfma_f32_16x16x32_bf16(a0, b0, acc[pj][0][0], 0, 0, 0);
      acc[pj][0][1] = __builtin_amdgcn_mfma_f32_16x16x32_bf16(a0, b1, acc[pj][0][1], 0, 0, 0);
      acc[pj][1][0] = __builtin_amdgcn_mfma_f32_16x16x32_bf16(a1, b0, acc[pj][1][0], 0, 0, 0);
      acc[pj][1][1] = __builtin_amdgcn_mfma_f32_16x16x32_bf16(a1, b1, acc[pj][1][1], 0, 0, 0);
    }
  }
#pragma unroll
  for (int pj = 0; pj < 3; pj++) {
    const float* bias = (pj == 0) ? bq : (pj == 1) ? bk : bv;
    // q pre-scaled by scale*log2e so attn's softmax is a bare exp2
    float sc = (pj == 0) ? SCLLOG : 1.0f;
    unsigned short* qk = (pj == 0) ? qt : kt;
#pragma unroll
    for (int rh = 0; rh < 2; rh++) {
      int od0 = oW + rh * 16 + quad * 4;           // 4 consecutive o rows
      float b0 = bias[od0], b1 = bias[od0+1], b2 = bias[od0+2], b3 = bias[od0+3];
#pragma unroll
      for (int ch = 0; ch < 2; ch++) {
        float v0 = acc[pj][rh][ch][0] + b0, v1 = acc[pj][rh][ch][1] + b1;
        float v2 = acc[pj][rh][ch][2] + b2, v3 = acc[pj][rh][ch][3] + b3;
        int p = pW + ch * 16 + l15;
        if (pj < 2) {
          int h2 = od0 >> 5, d0 = od0 & 31;
          uint2 pk;
          pk.x = cvt_pk_bf16(v0 * sc, v1 * sc);
          pk.y = cvt_pk_bf16(v2 * sc, v3 * sc);
          size_t idx = ((size_t)(b * NHD + h2) * NP + p) * HD + d0;
          *(uint2*)(qk + idx) = pk;
        } else {
          // v -> [b, c=o, p] bf16, m-linear (matches PV B-operand k=hi*8+j)
          size_t base = ((size_t)b * NC + od0) * NP + p;
          vt[base]          = f2b1(v0);
          vt[base +     NP] = f2b1(v1);
          vt[base + 2 * NP] = f2b1(v2);
          vt[base + 3 * NP] = f2b1(v3);
        }
      }
    }
  }
}

// ---------------- flash attention (swapped 32x32, 4 n-tiles/wave, split-m x4) --
// grid (8, 64); block = 256 threads = 4 waves. Block owns 128 q rows
// (n0 = bx*128; tiles a,b,c,d at n0, n0+32, n0+64, n0+96). Wave w covers
// m in [w*256, (w+1)*256), 8 tiles of 32; K/V fragments shared by all 4
// n-tiles. NAMED SCALARS throughout (R3's array form failed; this is the
// verified R2 body with tiles c,d duplicated verbatim).
// Per tile: S^T = mfma_32x32x16(K,Q) x2 -> col = n = lane&31,
//   row m = (r&3)+8*(r>>2)+4*hi (crow). p = 2^s in-register (scale folded
//   into Q, exact after 1/l). P->bf16 A-operand: 8 cvt_pk + 4
//   v_permlane32_swap_b32 (T12, verified R1/R2/R4).
// Combine: linear (no max): waves 1-3 dump (O,l) to LDS (stride 69 floats,
// odd -> bank-conflict-free), one __syncthreads, wave 0 adds and stores.
__global__ __launch_bounds__(256, 2) void attn_kernel(
    const unsigned short* __restrict__ qt, const unsigned short* __restrict__ kt,
    const unsigned short* __restrict__ vt, unsigned short* __restrict__ at) {
  int tid = threadIdx.x, wave = tid >> 6, lane = tid & 63;
  int l31 = lane & 31, hi = lane >> 5;
  int bh = blockIdx.y, b = bh >> 3, h = bh & 7;
  int n0 = blockIdx.x * 128;

  __shared__ float Comb[3][64][69];   // [wave-1][lane][64 O + 4 l + pad]
  __shared__ float Linv[4][32];       // [tile][n-in-tile] broadcast of 1/l

  // Q fragments (B-operand): col = n = lane&31, k = d = hi*8+j
  const unsigned short* qpa = qt + ((size_t)bh * NP + n0 + l31) * HD + hi * 8;
  bf16x8 qa0 = *(const bf16x8*)(qpa);
  bf16x8 qa1 = *(const bf16x8*)(qpa + 16);
  bf16x8 qb0 = *(const bf16x8*)(qpa + 32 * HD);
  bf16x8 qb1 = *(const bf16x8*)(qpa + 32 * HD + 16);
  bf16x8 qc0 = *(const bf16x8*)(qpa + 64 * HD);
  bf16x8 qc1 = *(const bf16x8*)(qpa + 64 * HD + 16);
  bf16x8 qd0 = *(const bf16x8*)(qpa + 96 * HD);
  bf16x8 qd1 = *(const bf16x8*)(qpa + 96 * HD + 16);

  // K rows (A-operand): row = m, k = d = hi*8+j
  const unsigned short* kp = kt + ((size_t)bh * NP + l31) * HD + hi * 8;
  // V (B-operand): col = d = lane&31, k = m = hi*8+j (m-linear layout)
  const unsigned short* vp = vt + ((size_t)(b * NC + h * HD + l31)) * NP + hi * 8;

  f32x16 oa = F32X16_ZERO, ob = F32X16_ZERO;
  f32x16 oc = F32X16_ZERO, od = F32X16_ZERO;
  f32x4 la = (f32x4){0.f, 0.f, 0.f, 0.f}, lb = (f32x4){0.f, 0.f, 0.f, 0.f};
  f32x4 lc = (f32x4){0.f, 0.f, 0.f, 0.f}, ld = (f32x4){0.f, 0.f, 0.f, 0.f};

  int mbase = wave * 256;
  bf16x8 kf0 = *(const bf16x8*)(kp + (size_t)mbase * HD);
  bf16x8 kf1 = *(const bf16x8*)(kp + (size_t)mbase * HD + 16);
  bf16x8 vf0 = *(const bf16x8*)(vp + mbase);
  bf16x8 vf1 = *(const bf16x8*)(vp + mbase + 16);

  for (int m0 = mbase; m0 < mbase + 256; m0 += 32) {
    // prefetch next tile (tail over-read stays inside ws buffers)
    bf16x8 nk0 = *(const bf16x8*)(kp + (size_t)(m0 + 32) * HD);
    bf16x8 nk1 = *(const bf16x8*)(kp + (size_t)(m0 + 32) * HD + 16);
    bf16x8 nv0 = *(const bf16x8*)(vp + m0 + 32);
    bf16x8 nv1 = *(const bf16x8*)(vp + m0 + 48);

    // ---- tiles a,b (verbatim R2 body) ----
    f32x16 sa = __builtin_amdgcn_mfma_f32_32x32x16_bf16(kf0, qa0, F32X16_ZERO, 0, 0, 0);
    f32x16 sb = __builtin_amdgcn_mfma_f32_32x32x16_bf16(kf0, qb0, F32X16_ZERO, 0, 0, 0);
    sa = __builtin_amdgcn_mfma_f32_32x32x16_bf16(kf1, qa1, sa, 0, 0, 0);
    sb = __builtin_amdgcn_mfma_f32_32x32x16_bf16(kf1, qb1, sb, 0, 0, 0);
    float pa[16], pb[16];
#pragma unroll
    for (int r = 0; r < 16; r++) pa[r] = __builtin_amdgcn_exp2f(sa[r]);
#pragma unroll
    for (int r = 0; r < 16; r++) pb[r] = __builtin_amdgcn_exp2f(sb[r]);
#pragma unroll
    for (int r = 0; r < 16; r++) { la[r & 3] += pa[r]; lb[r & 3] += pb[r]; }
    unsigned a0 = cvt_pk_bf16(pa[0],  pa[1]),  a1 = cvt_pk_bf16(pa[2],  pa[3]);
    unsigned a2 = cvt_pk_bf16(pa[4],  pa[5]),  a3 = cvt_pk_bf16(pa[6],  pa[7]);
    unsigned a4 = cvt_pk_bf16(pa[8],  pa[9]),  a5 = cvt_pk_bf16(pa[10], pa[11]);
    unsigned a6 = cvt_pk_bf16(pa[12], pa[13]), a7 = cvt_pk_bf16(pa[14], pa[15]);
    asm("v_permlane32_swap_b32 %0, %1" : "+v"(a0), "+v"(a2));
    asm("v_permlane32_swap_b32 %0, %1" : "+v"(a1), "+v"(a3));
    asm("v_permlane32_swap_b32 %0, %1" : "+v"(a4), "+v"(a6));
    asm("v_permlane32_swap_b32 %0, %1" : "+v"(a5), "+v"(a7));
    unsigned b0 = cvt_pk_bf16(pb[0],  pb[1]),  b1 = cvt_pk_bf16(pb[2],  pb[3]);
    unsigned b2 = cvt_pk_bf16(pb[4],  pb[5]),  b3 = cvt_pk_bf16(pb[6],  pb[7]);
    unsigned b4 = cvt_pk_bf16(pb[8],  pb[9]),  b5 = cvt_pk_bf16(pb[10], pb[11]);
    unsigned b6 = cvt_pk_bf16(pb[12], pb[13]), b7 = cvt_pk_bf16(pb[14], pb[15]);
    asm("v_permlane32_swap_b32 %0, %1" : "+v"(b0), "+v"(b2));
    asm("v_permlane32_swap_b32 %0, %1" : "+v"(b1), "+v"(b3));
    asm("v_permlane32_swap_b32 %0, %1" : "+v"(b4), "+v"(b6));
    asm("v_permlane32_swap_b32 %0, %1" : "+v"(b5), "+v"(b7));
    union { unsigned u[4]; bf16x8 v; } fa0, fa1, fb0, fb1;
    fa0.u[0] = a0; fa0.u[1] = a1; fa0.u[2] = a2; fa0.u[3] = a3;
    fa1.u[0] = a4; fa1.u[1] = a5; fa1.u[2] = a6; fa1.u[3] = a7;
    fb0.u[0] = b0; fb0.u[1] = b1; fb0.u[2] = b2; fb0.u[3] = b3;
    fb1.u[0] = b4; fb1.u[1] = b5; fb1.u[2] = b6; fb1.u[3] = b7;
    oa = __builtin_amdgcn_mfma_f32_32x32x16_bf16(fa0.v, vf0, oa, 0, 0, 0);
    oa = __builtin_amdgcn_mfma_f32_32x32x16_bf16(fa1.v, vf1, oa, 0, 0, 0);
    ob = __builtin_amdgcn_mfma_f32_32x32x16_bf16(fb0.v, vf0, ob, 0, 0, 0);
    ob = __builtin_amdgcn_mfma_f32_32x32x16_bf16(fb1.v, vf1, ob, 0, 0, 0);

    // ---- tiles c,d (verbatim duplicate) ----
    f32x16 sc = __builtin_amdgcn_mfma_f32_32x32x16_bf16(kf0, qc0, F32X16_ZERO, 0, 0, 0);
    f32x16 sd = __builtin_amdgcn_mfma_f32_32x32x16_bf16(kf0, qd0, F32X16_ZERO, 0, 0, 0);
    sc = __builtin_amdgcn_mfma_f32_32x32x16_bf16(kf1, qc1, sc, 0, 0, 0);
    sd = __builtin_amdgcn_mfma_f32_32x32x16_bf16(kf1, qd1, sd, 0, 0, 0);
    float pc[16], pd[16];
#pragma unroll
    for (int r = 0; r < 16; r++) pc[r] = __builtin_amdgcn_exp2f(sc[r]);
#pragma unroll
    for (int r = 0; r < 16; r++) pd[r] = __builtin_amdgcn_exp2f(sd[r]);
#pragma unroll
    for (int r = 0; r < 16; r++) { lc[r & 3] += pc[r]; ld[r & 3] += pd[r]; }
    unsigned c0 = cvt_pk_bf16(pc[0],  pc[1]),  c1 = cvt_pk_bf16(pc[2],  pc[3]);
    unsigned c2 = cvt_pk_bf16(pc[4],  pc[5]),  c3 = cvt_pk_bf16(pc[6],  pc[7]);
    unsigned c4 = cvt_pk_bf16(pc[8],  pc[9]),  c5 = cvt_pk_bf16(pc[10], pc[11]);
    unsigned c6 = cvt_pk_bf16(pc[12], pc[13]), c7 = cvt_pk_bf16(pc[14], pc[15]);
    asm("v_permlane32_swap_b32 %0, %1" : "+v"(c0), "+v"(c2));
    asm("v_permlane32_swap_b32 %0, %1" : "+v"(c1), "+v"(c3));
    asm("v_permlane32_swap_b32 %0, %1" : "+v"(c4), "+v"(c6));
    asm("v_permlane32_swap_b32 %0, %1" : "+v"(c5), "+v"(c7));
    unsigned d0 = cvt_pk_bf16(pd[0],  pd[1]),  d1 = cvt_pk_bf16(pd[2],  pd[3]);
    unsigned d2 = cvt_pk_bf16(pd[4],  pd[5]),  d3 = cvt_pk_bf16(pd[6],  pd[7]);
    unsigned d4 = cvt_pk_bf16(pd[8],  pd[9]),  d5 = cvt_pk_bf16(pd[10], pd[11]);
    unsigned d6 = cvt_pk_bf16(pd[12], pd[13]), d7 = cvt_pk_bf16(pd[14], pd[15]);
    asm("v_permlane32_swap_b32 %0, %1" : "+v"(d0), "+v"(d2));
    asm("v_permlane32_swap_b32 %0, %1" : "+v"(d1), "+v"(d3));
    asm("v_permlane32_swap_b32 %0, %1" : "+v"(d4), "+v"(d6));
    asm("v_permlane32_swap_b32 %0, %1" : "+v"(d5), "+v"(d7));
    union { unsigned u[4]; bf16x8 v; } fc0, fc1, fd0, fd1;
    fc0.u[0] = c0; fc0.u[1] = c1; fc0.u[2] = c2; fc0.u[3] = c3;
    fc1.u[0] = c4; fc1.u[1] = c5; fc1.u[2] = c6; fc1.u[3] = c7;
    fd0.u[0] = d0; fd0.u[1] = d1; fd0.u[2] = d2; fd0.u[3] = d3;
    fd1.u[0] = d4; fd1.u[1] = d5; fd1.u[2] = d6; fd1.u[3] = d7;
    oc = __builtin_amdgcn_mfma_f32_32x32x16_bf16(fc0.v, vf0, oc, 0, 0, 0);
    oc = __builtin_amdgcn_mfma_f32_32x32x16_bf16(fc1.v, vf1, oc, 0, 0, 0);
    od = __builtin_amdgcn_mfma_f32_32x32x16_bf16(fd0.v, vf0, od, 0, 0, 0);
    od = __builtin_amdgcn_mfma_f32_32x32x16_bf16(fd1.v, vf1, od, 0, 0, 0);

    kf0 = nk0; kf1 = nk1; vf0 = nv0; vf1 = nv1;
  }

  // lane-pair combine of l (lane and lane^32 hold complementary m rows)
  float lsA = (la[0] + la[1]) + (la[2] + la[3]);
  float lsB = (lb[0] + lb[1]) + (lb[2] + lb[3]);
  float lsC = (lc[0] + lc[1]) + (lc[2] + lc[3]);
  float lsD = (ld[0] + ld[1]) + (ld[2] + ld[3]);
  lsA += __shfl_xor(lsA, 32, 64);
  lsB += __shfl_xor(lsB, 32, 64);
  lsC += __shfl_xor(lsC, 32, 64);
  lsD += __shfl_xor(lsD, 32, 64);

  // ---- combine m-quarters (linear: static softmax -> no rescale) ----
  if (wave) {
    float* Cb = &Comb[wave - 1][lane][0];
#pragma unroll
    for (int r = 0; r < 16; r++) {
      Cb[r] = oa[r]; Cb[16 + r] = ob[r]; Cb[32 + r] = oc[r]; Cb[48 + r] = od[r];
    }
    Cb[64] = lsA; Cb[65] = lsB; Cb[66] = lsC; Cb[67] = lsD;
  }
  __syncthreads();
  if (wave == 0) {
#pragma unroll
    for (int w = 0; w < 3; w++) {
      const float* Cb = &Comb[w][lane][0];
#pragma unroll
      for (int r = 0; r < 16; r++) {
        oa[r] += Cb[r]; ob[r] += Cb[16 + r]; oc[r] += Cb[32 + r]; od[r] += Cb[48 + r];
      }
      lsA += Cb[64]; lsB += Cb[65]; lsC += Cb[66]; lsD += Cb[67];
    }
    if (hi == 0) {
      Linv[0][l31] = 1.0f / lsA;    // same-wave RAW: compiler waits
      Linv[1][l31] = 1.0f / lsB;
      Linv[2][l31] = 1.0f / lsC;
      Linv[3][l31] = 1.0f / lsD;
    }
    // O[n = n0+tile*32+crow(r,hi), d = l31] -> at[b, n, c = d*8 + h]
    unsigned short* ab = at + (size_t)b * NP * NC + (size_t)(l31 * 8 + h);
#pragma unroll
    for (int r = 0; r < 16; r++) {
      int crow = (r & 3) + 8 * (r >> 2) + 4 * hi;
      ab[(size_t)(n0 + crow) * NC]       = f2b1(oa[r] * Linv[0][crow]);
      ab[(size_t)(n0 + 32 + crow) * NC]  = f2b1(ob[r] * Linv[1][crow]);
      ab[(size_t)(n0 + 64 + crow) * NC]  = f2b1(oc[r] * Linv[2][crow]);
      ab[(size_t)(n0 + 96 + crow) * NC]  = f2b1(od[r] * Linv[3][crow]);
    }
  }
}

// ---------------- output projection ----------------
__global__ __launch_bounds__(256) void mproj_kernel(
    const unsigned short* __restrict__ Wmb, const float* __restrict__ bm,
    const unsigned short* __restrict__ at, float* __restrict__ out) {
  int b = blockIdx.y, bx = blockIdx.x;
  int ot = (bx & 3) * 64, pt = (bx >> 2) * 64;
  int tid = threadIdx.x, wave = tid >> 6, lane = tid & 63;
  int l15 = lane & 15, quad = lane >> 4;
  int oW = ot + (wave & 1) * 32, pW = pt + (wave >> 1) * 32;
  const unsigned short* A0 = Wmb + (size_t)(oW + l15) * NC + quad * 8;
  const unsigned short* B0 = at + ((size_t)b * NP + pW + l15) * NC + quad * 8;
  f32x4 acc[2][2];
#pragma unroll
  for (int i = 0; i < 2; i++)
#pragma unroll
    for (int j = 0; j < 2; j++) acc[i][j] = (f32x4){0.f, 0.f, 0.f, 0.f};
#pragma unroll
  for (int c0 = 0; c0 < NC; c0 += 32) {
    bf16x8 a0 = *(const bf16x8*)(A0 + c0);
    bf16x8 a1 = *(const bf16x8*)(A0 + 16 * NC + c0);
    bf16x8 b0 = *(const bf16x8*)(B0 + c0);
    bf16x8 b1 = *(const bf16x8*)(B0 + 16 * NC + c0);
    acc[0][0] = __builtin_amdgcn_mfma_f32_16x16x32_bf16(a0, b0, acc[0][0], 0, 0, 0);
    acc[0][1] = __builtin_amdgcn_mfma_f32_16x16x32_bf16(a0, b1, acc[0][1], 0, 0, 0);
    acc[1][0] = __builtin_amdgcn_mfma_f32_16x16x32_bf16(a1, b0, acc[1][0], 0, 0, 0);
    acc[1][1] = __builtin_amdgcn_mfma_f32_16x16x32_bf16(a1, b1, acc[1][1], 0, 0, 0);
  }
#pragma unroll
  for (int rh = 0; rh < 2; rh++) {
    int od0 = oW + rh * 16 + quad * 4;
    float b0 = bm[od0], b1 = bm[od0+1], b2 = bm[od0+2], b3 = bm[od0+3];
#pragma unroll
    for (int ch = 0; ch < 2; ch++) {
      int p = pW + ch * 16 + l15;
      size_t base = ((size_t)b * NC + od0) * NP + p;
      out[base]          = acc[rh][ch][0] + b0;
      out[base +     NP] = acc[rh][ch][1] + b1;
      out[base + 2 * NP] = acc[rh][ch][2] + b2;
      out[base + 3 * NP] = acc[rh][ch][3] + b3;
    }
  }
}

extern "C" void kernel_launch(void* const* d_in, const int* in_sizes, int n_in,
                              void* d_out, int out_size, void* d_ws, size_t ws_size,
                              hipStream_t stream) {
  (void)in_sizes; (void)n_in; (void)out_size; (void)ws_size;
  const float* x  = (const float*)d_in[0];
  const float* Wq = (const float*)d_in[1];
  const float* bq = (const float*)d_in[2];
  const float* Wk = (const float*)d_in[3];
  const float* bk = (const float*)d_in[4];
  const float* Wv = (const float*)d_in[5];
  const float* bv = (const float*)d_in[6];
  const float* Wm = (const float*)d_in[7];
  const float* bm = (const float*)d_in[8];
  float* out = (float*)d_out;
  char* ws = (char*)d_ws;

  unsigned short* xt = (unsigned short*)(ws);                              // 4 MB
  unsigned short* Wb = (unsigned short*)(ws + (4u << 20));                 // 512 KB
  unsigned short* qt = (unsigned short*)(ws + (4u << 20) + (512u << 10));  // 4 MB
  unsigned short* kt = (unsigned short*)(ws + (8u << 20) + (512u << 10));  // 4 MB
  unsigned short* vt = (unsigned short*)(ws + (12u << 20) + (512u << 10)); // 4 MB
  unsigned short* at = (unsigned short*)(ws + (16u << 20) + (512u << 10)); // 4 MB

  prep_kernel<<<640, 256, 0, stream>>>(Wq, Wk, Wv, Wm, x, Wb, xt);
  qkv_kernel<<<dim3(64, 8), 256, 0, stream>>>(Wb, bq, bk, bv, xt, qt, kt, vt);
  attn_kernel<<<dim3(8, 64), 256, 0, stream>>>(qt, kt, vt, at);
  mproj_kernel<<<dim3(64, 8), 256, 0, stream>>>(Wb + 3 * 65536, bm, at, out);
}

// Round 7
// 118.032 us; speedup vs baseline: 1.1778x; 1.0465x over previous
//
#include <hip/hip_runtime.h>
#include <cstdint>
#include <cstddef>

// SelfAttention: B=8, C=256, H=W=32, HEADS=8, hd=32, N=HW=1024
// Pipeline (all bf16 MFMA, fp32 accum):
//   prep:  W[4] fp32->bf16 ; x [b,c,p] fp32 -> xt [b,p,c] bf16 (LDS transpose)
//   qkv :  3 projections fused; R7: 64o x 128p blocks (grid 32x8) -> W
//          re-read traffic 49->24.5MB. q pre-scaled by scale*log2e.
//   attn:  R5-VERBATIM FROZEN (passing at 123.5us). 4 n-tiles (128 q rows)
//          per wave, named scalars, swapped 32x32x16, in-register softmax
//          (T12), SPLIT-M x4, linear LDS combine (stride 69).
//          NOTE: R3 (array form) and R6 (8-wave ctx) both MISCOMPILED this
//          body -> no further structural edits to attn.
//   mproj: R7: 64o x 128p blocks -> Wm traffic 16->8MB.
// ws layout: xt 4MB | Wb 512KB | qt 4MB | kt 4MB | vt 4MB | at 4MB  = 20.5 MB

#define NB 8
#define NC 256
#define NP 1024
#define NHD 8
#define HD 32

typedef short bf16x8 __attribute__((ext_vector_type(8)));
typedef float f32x4 __attribute__((ext_vector_type(4)));
typedef float f32x16 __attribute__((ext_vector_type(16)));

// scale * log2(e) : softmax(s/sqrt(32)) computed as 2^(s*SCLLOG)
#define SCLLOG 0.25505654356918f

#define F32X16_ZERO (f32x16){0.f,0.f,0.f,0.f,0.f,0.f,0.f,0.f,0.f,0.f,0.f,0.f,0.f,0.f,0.f,0.f}

// hardware packed fp32->bf16 (RNE): D.lo = bf16(a), D.hi = bf16(b)
__device__ __forceinline__ unsigned cvt_pk_bf16(float a, float b) {
  unsigned r;
  asm("v_cvt_pk_bf16_f32 %0, %1, %2" : "=v"(r) : "v"(a), "v"(b));
  return r;
}
__device__ __forceinline__ unsigned short f2b1(float a) {
  return (unsigned short)cvt_pk_bf16(a, a);
}

// ---------------- prep: weight cvt + x transpose ----------------
__global__ __launch_bounds__(256) void prep_kernel(
    const float* __restrict__ Wq, const float* __restrict__ Wk,
    const float* __restrict__ Wv, const float* __restrict__ Wm,
    const float* __restrict__ x, unsigned short* __restrict__ Wb,
    unsigned short* __restrict__ xt) {
  __shared__ float sx[64][65];
  int bx = blockIdx.x, tid = threadIdx.x;
  if (bx < 128) {
    int idx = (bx * 256 + tid) * 8;
    const float* src; int off;
    if (idx < 65536)       { src = Wq; off = idx; }
    else if (idx < 131072) { src = Wk; off = idx - 65536; }
    else if (idx < 196608) { src = Wv; off = idx - 131072; }
    else                   { src = Wm; off = idx - 196608; }
    float4 lo = *(const float4*)(src + off);
    float4 hi = *(const float4*)(src + off + 4);
    union { unsigned u[4]; bf16x8 v; } o;
    o.u[0] = cvt_pk_bf16(lo.x, lo.y); o.u[1] = cvt_pk_bf16(lo.z, lo.w);
    o.u[2] = cvt_pk_bf16(hi.x, hi.y); o.u[3] = cvt_pk_bf16(hi.z, hi.w);
    *(bf16x8*)(Wb + idx) = o.v;
  } else {
    // transpose one 64c x 64p tile: x[b,c,p] fp32 -> xt[b,p,c] bf16
    int bi = bx - 128;
    int b = bi >> 6, rest = bi & 63;
    int ct = (rest & 3) * 64, pt = (rest >> 2) * 64;
    const float* xb = x + ((size_t)(b * NC + ct)) * NP + pt;
    int pr = (tid & 15) * 4, cr = tid >> 4;
#pragma unroll
    for (int i = 0; i < 4; i++) {
      float4 v = *(const float4*)(xb + (size_t)(cr + i * 16) * NP + pr);
      sx[cr + i*16][pr]   = v.x; sx[cr + i*16][pr+1] = v.y;
      sx[cr + i*16][pr+2] = v.z; sx[cr + i*16][pr+3] = v.w;
    }
    __syncthreads();
    int pl = tid >> 3, cc = (tid & 7) * 8;
#pragma unroll
    for (int j = 0; j < 2; j++) {
      int p = pl + j * 32;
      union { unsigned u[4]; bf16x8 v; } o;
#pragma unroll
      for (int u = 0; u < 4; u++)
        o.u[u] = cvt_pk_bf16(sx[cc + 2*u][p], sx[cc + 2*u + 1][p]);
      *(bf16x8*)(xt + ((size_t)b * NP + pt + p) * NC + ct + cc) = o.v;
    }
  }
}

// ---------------- QKV projection GEMM (3 proj fused, 64o x 128p) ----------
__global__ __launch_bounds__(256) void qkv_kernel(
    const unsigned short* __restrict__ Wb,
    const float* __restrict__ bq, const float* __restrict__ bk,
    const float* __restrict__ bv,
    const unsigned short* __restrict__ xt,
    unsigned short* __restrict__ qt, unsigned short* __restrict__ kt,
    unsigned short* __restrict__ vt) {
  int b = blockIdx.y, bx = blockIdx.x;
  int ot = (bx & 3) * 64, pt = (bx >> 2) * 128;     // 4 o-tiles x 8 p-tiles
  int tid = threadIdx.x, wave = tid >> 6, lane = tid & 63;
  int l15 = lane & 15, quad = lane >> 4;
  int oW = ot + (wave & 1) * 32, pW = pt + (wave >> 1) * 64;  // 32o x 64p / wave
  const unsigned short* A0 = Wb + (size_t)(oW + l15) * NC + quad * 8;
  const unsigned short* B0 = xt + ((size_t)b * NP + pW + l15) * NC + quad * 8;
  f32x4 acc[3][2][4];
#pragma unroll
  for (int pj = 0; pj < 3; pj++)
#pragma unroll
    for (int i = 0; i < 2; i++)
#pragma unroll
      for (int j = 0; j < 4; j++) acc[pj][i][j] = (f32x4){0.f, 0.f, 0.f, 0.f};
#pragma unroll
  for (int c0 = 0; c0 < NC; c0 += 32) {
    // xt B-fragments loaded once, reused by all 3 projections
    bf16x8 bb0 = *(const bf16x8*)(B0 + c0);
    bf16x8 bb1 = *(const bf16x8*)(B0 + 16 * NC + c0);
    bf16x8 bb2 = *(const bf16x8*)(B0 + 32 * NC + c0);
    bf16x8 bb3 = *(const bf16x8*)(B0 + 48 * NC + c0);
#pragma unroll
    for (int pj = 0; pj < 3; pj++) {
      bf16x8 a0 = *(const bf16x8*)(A0 + pj * 65536 + c0);
      bf16x8 a1 = *(const bf16x8*)(A0 + pj * 65536 + 16 * NC + c0);
      acc[pj][0][0] = __builtin_amdgcn_mfma_f32_16x16x32_bf16(a0, bb0, acc[pj][0][0], 0, 0, 0);
      acc[pj][0][1] = __builtin_amdgcn_mfma_f32_16x16x32_bf16(a0, bb1, acc[pj][0][1], 0, 0, 0);
      acc[pj][0][2] = __builtin_amdgcn_mfma_f32_16x16x32_bf16(a0, bb2, acc[pj][0][2], 0, 0, 0);
      acc[pj][0][3] = __builtin_amdgcn_mfma_f32_16x16x32_bf16(a0, bb3, acc[pj][0][3], 0, 0, 0);
      acc[pj][1][0] = __builtin_amdgcn_mfma_f32_16x16x32_bf16(a1, bb0, acc[pj][1][0], 0, 0, 0);
      acc[pj][1][1] = __builtin_amdgcn_mfma_f32_16x16x32_bf16(a1, bb1, acc[pj][1][1], 0, 0, 0);
      acc[pj][1][2] = __builtin_amdgcn_mfma_f32_16x16x32_bf16(a1, bb2, acc[pj][1][2], 0, 0, 0);
      acc[pj][1][3] = __builtin_amdgcn_mfma_f32_16x16x32_bf16(a1, bb3, acc[pj][1][3], 0, 0, 0);
    }
  }
#pragma unroll
  for (int pj = 0; pj < 3; pj++) {
    const float* bias = (pj == 0) ? bq : (pj == 1) ? bk : bv;
    // q pre-scaled by scale*log2e so attn's softmax is a bare exp2
    float sc = (pj == 0) ? SCLLOG : 1.0f;
    unsigned short* qk = (pj == 0) ? qt : kt;
#pragma unroll
    for (int rh = 0; rh < 2; rh++) {
      int od0 = oW + rh * 16 + quad * 4;           // 4 consecutive o rows
      float b0 = bias[od0], b1 = bias[od0+1], b2 = bias[od0+2], b3 = bias[od0+3];
#pragma unroll
      for (int ch = 0; ch < 4; ch++) {
        float v0 = acc[pj][rh][ch][0] + b0, v1 = acc[pj][rh][ch][1] + b1;
        float v2 = acc[pj][rh][ch][2] + b2, v3 = acc[pj][rh][ch][3] + b3;
        int p = pW + ch * 16 + l15;
        if (pj < 2) {
          int h2 = od0 >> 5, d0 = od0 & 31;
          uint2 pk;
          pk.x = cvt_pk_bf16(v0 * sc, v1 * sc);
          pk.y = cvt_pk_bf16(v2 * sc, v3 * sc);
          size_t idx = ((size_t)(b * NHD + h2) * NP + p) * HD + d0;
          *(uint2*)(qk + idx) = pk;
        } else {
          // v -> [b, c=o, p] bf16, m-linear (matches PV B-operand k=hi*8+j)
          size_t base = ((size_t)b * NC + od0) * NP + p;
          vt[base]          = f2b1(v0);
          vt[base +     NP] = f2b1(v1);
          vt[base + 2 * NP] = f2b1(v2);
          vt[base + 3 * NP] = f2b1(v3);
        }
      }
    }
  }
}

// ---------------- flash attention (swapped 32x32, 4 n-tiles/wave, split-m x4) --
// R5-VERBATIM, FROZEN. grid (8, 64); block = 256 threads = 4 waves. Block
// owns 128 q rows (n0 = bx*128; tiles a,b,c,d at n0, n0+32, n0+64, n0+96).
// Wave w covers m in [w*256, (w+1)*256), 8 tiles of 32; K/V fragments
// shared by all 4 n-tiles. NAMED SCALARS throughout (R3 array form and R6
// 8-wave context both miscompiled; do not restructure).
// Per tile: S^T = mfma_32x32x16(K,Q) x2 -> col = n = lane&31,
//   row m = (r&3)+8*(r>>2)+4*hi (crow). p = 2^s in-register (scale folded
//   into Q, exact after 1/l). P->bf16 A-operand: 8 cvt_pk + 4
//   v_permlane32_swap_b32 (T12, verified R1/R2/R4/R5).
// Combine: linear (no max): waves 1-3 dump (O,l) to LDS (stride 69 floats,
// odd -> bank-conflict-free), one __syncthreads, wave 0 adds and stores.
__global__ __launch_bounds__(256, 2) void attn_kernel(
    const unsigned short* __restrict__ qt, const unsigned short* __restrict__ kt,
    const unsigned short* __restrict__ vt, unsigned short* __restrict__ at) {
  int tid = threadIdx.x, wave = tid >> 6, lane = tid & 63;
  int l31 = lane & 31, hi = lane >> 5;
  int bh = blockIdx.y, b = bh >> 3, h = bh & 7;
  int n0 = blockIdx.x * 128;

  __shared__ float Comb[3][64][69];   // [wave-1][lane][64 O + 4 l + pad]
  __shared__ float Linv[4][32];       // [tile][n-in-tile] broadcast of 1/l

  // Q fragments (B-operand): col = n = lane&31, k = d = hi*8+j
  const unsigned short* qpa = qt + ((size_t)bh * NP + n0 + l31) * HD + hi * 8;
  bf16x8 qa0 = *(const bf16x8*)(qpa);
  bf16x8 qa1 = *(const bf16x8*)(qpa + 16);
  bf16x8 qb0 = *(const bf16x8*)(qpa + 32 * HD);
  bf16x8 qb1 = *(const bf16x8*)(qpa + 32 * HD + 16);
  bf16x8 qc0 = *(const bf16x8*)(qpa + 64 * HD);
  bf16x8 qc1 = *(const bf16x8*)(qpa + 64 * HD + 16);
  bf16x8 qd0 = *(const bf16x8*)(qpa + 96 * HD);
  bf16x8 qd1 = *(const bf16x8*)(qpa + 96 * HD + 16);

  // K rows (A-operand): row = m, k = d = hi*8+j
  const unsigned short* kp = kt + ((size_t)bh * NP + l31) * HD + hi * 8;
  // V (B-operand): col = d = lane&31, k = m = hi*8+j (m-linear layout)
  const unsigned short* vp = vt + ((size_t)(b * NC + h * HD + l31)) * NP + hi * 8;

  f32x16 oa = F32X16_ZERO, ob = F32X16_ZERO;
  f32x16 oc = F32X16_ZERO, od = F32X16_ZERO;
  f32x4 la = (f32x4){0.f, 0.f, 0.f, 0.f}, lb = (f32x4){0.f, 0.f, 0.f, 0.f};
  f32x4 lc = (f32x4){0.f, 0.f, 0.f, 0.f}, ld = (f32x4){0.f, 0.f, 0.f, 0.f};

  int mbase = wave * 256;
  bf16x8 kf0 = *(const bf16x8*)(kp + (size_t)mbase * HD);
  bf16x8 kf1 = *(const bf16x8*)(kp + (size_t)mbase * HD + 16);
  bf16x8 vf0 = *(const bf16x8*)(vp + mbase);
  bf16x8 vf1 = *(const bf16x8*)(vp + mbase + 16);

  for (int m0 = mbase; m0 < mbase + 256; m0 += 32) {
    // prefetch next tile (tail over-read stays inside ws buffers)
    bf16x8 nk0 = *(const bf16x8*)(kp + (size_t)(m0 + 32) * HD);
    bf16x8 nk1 = *(const bf16x8*)(kp + (size_t)(m0 + 32) * HD + 16);
    bf16x8 nv0 = *(const bf16x8*)(vp + m0 + 32);
    bf16x8 nv1 = *(const bf16x8*)(vp + m0 + 48);

    // ---- tiles a,b (verbatim R2 body) ----
    f32x16 sa = __builtin_amdgcn_mfma_f32_32x32x16_bf16(kf0, qa0, F32X16_ZERO, 0, 0, 0);
    f32x16 sb = __builtin_amdgcn_mfma_f32_32x32x16_bf16(kf0, qb0, F32X16_ZERO, 0, 0, 0);
    sa = __builtin_amdgcn_mfma_f32_32x32x16_bf16(kf1, qa1, sa, 0, 0, 0);
    sb = __builtin_amdgcn_mfma_f32_32x32x16_bf16(kf1, qb1, sb, 0, 0, 0);
    float pa[16], pb[16];
#pragma unroll
    for (int r = 0; r < 16; r++) pa[r] = __builtin_amdgcn_exp2f(sa[r]);
#pragma unroll
    for (int r = 0; r < 16; r++) pb[r] = __builtin_amdgcn_exp2f(sb[r]);
#pragma unroll
    for (int r = 0; r < 16; r++) { la[r & 3] += pa[r]; lb[r & 3] += pb[r]; }
    unsigned a0 = cvt_pk_bf16(pa[0],  pa[1]),  a1 = cvt_pk_bf16(pa[2],  pa[3]);
    unsigned a2 = cvt_pk_bf16(pa[4],  pa[5]),  a3 = cvt_pk_bf16(pa[6],  pa[7]);
    unsigned a4 = cvt_pk_bf16(pa[8],  pa[9]),  a5 = cvt_pk_bf16(pa[10], pa[11]);
    unsigned a6 = cvt_pk_bf16(pa[12], pa[13]), a7 = cvt_pk_bf16(pa[14], pa[15]);
    asm("v_permlane32_swap_b32 %0, %1" : "+v"(a0), "+v"(a2));
    asm("v_permlane32_swap_b32 %0, %1" : "+v"(a1), "+v"(a3));
    asm("v_permlane32_swap_b32 %0, %1" : "+v"(a4), "+v"(a6));
    asm("v_permlane32_swap_b32 %0, %1" : "+v"(a5), "+v"(a7));
    unsigned b0 = cvt_pk_bf16(pb[0],  pb[1]),  b1 = cvt_pk_bf16(pb[2],  pb[3]);
    unsigned b2 = cvt_pk_bf16(pb[4],  pb[5]),  b3 = cvt_pk_bf16(pb[6],  pb[7]);
    unsigned b4 = cvt_pk_bf16(pb[8],  pb[9]),  b5 = cvt_pk_bf16(pb[10], pb[11]);
    unsigned b6 = cvt_pk_bf16(pb[12], pb[13]), b7 = cvt_pk_bf16(pb[14], pb[15]);
    asm("v_permlane32_swap_b32 %0, %1" : "+v"(b0), "+v"(b2));
    asm("v_permlane32_swap_b32 %0, %1" : "+v"(b1), "+v"(b3));
    asm("v_permlane32_swap_b32 %0, %1" : "+v"(b4), "+v"(b6));
    asm("v_permlane32_swap_b32 %0, %1" : "+v"(b5), "+v"(b7));
    union { unsigned u[4]; bf16x8 v; } fa0, fa1, fb0, fb1;
    fa0.u[0] = a0; fa0.u[1] = a1; fa0.u[2] = a2; fa0.u[3] = a3;
    fa1.u[0] = a4; fa1.u[1] = a5; fa1.u[2] = a6; fa1.u[3] = a7;
    fb0.u[0] = b0; fb0.u[1] = b1; fb0.u[2] = b2; fb0.u[3] = b3;
    fb1.u[0] = b4; fb1.u[1] = b5; fb1.u[2] = b6; fb1.u[3] = b7;
    oa = __builtin_amdgcn_mfma_f32_32x32x16_bf16(fa0.v, vf0, oa, 0, 0, 0);
    oa = __builtin_amdgcn_mfma_f32_32x32x16_bf16(fa1.v, vf1, oa, 0, 0, 0);
    ob = __builtin_amdgcn_mfma_f32_32x32x16_bf16(fb0.v, vf0, ob, 0, 0, 0);
    ob = __builtin_amdgcn_mfma_f32_32x32x16_bf16(fb1.v, vf1, ob, 0, 0, 0);

    // ---- tiles c,d (verbatim duplicate) ----
    f32x16 sc = __builtin_amdgcn_mfma_f32_32x32x16_bf16(kf0, qc0, F32X16_ZERO, 0, 0, 0);
    f32x16 sd = __builtin_amdgcn_mfma_f32_32x32x16_bf16(kf0, qd0, F32X16_ZERO, 0, 0, 0);
    sc = __builtin_amdgcn_mfma_f32_32x32x16_bf16(kf1, qc1, sc, 0, 0, 0);
    sd = __builtin_amdgcn_mfma_f32_32x32x16_bf16(kf1, qd1, sd, 0, 0, 0);
    float pc[16], pd[16];
#pragma unroll
    for (int r = 0; r < 16; r++) pc[r] = __builtin_amdgcn_exp2f(sc[r]);
#pragma unroll
    for (int r = 0; r < 16; r++) pd[r] = __builtin_amdgcn_exp2f(sd[r]);
#pragma unroll
    for (int r = 0; r < 16; r++) { lc[r & 3] += pc[r]; ld[r & 3] += pd[r]; }
    unsigned c0 = cvt_pk_bf16(pc[0],  pc[1]),  c1 = cvt_pk_bf16(pc[2],  pc[3]);
    unsigned c2 = cvt_pk_bf16(pc[4],  pc[5]),  c3 = cvt_pk_bf16(pc[6],  pc[7]);
    unsigned c4 = cvt_pk_bf16(pc[8],  pc[9]),  c5 = cvt_pk_bf16(pc[10], pc[11]);
    unsigned c6 = cvt_pk_bf16(pc[12], pc[13]), c7 = cvt_pk_bf16(pc[14], pc[15]);
    asm("v_permlane32_swap_b32 %0, %1" : "+v"(c0), "+v"(c2));
    asm("v_permlane32_swap_b32 %0, %1" : "+v"(c1), "+v"(c3));
    asm("v_permlane32_swap_b32 %0, %1" : "+v"(c4), "+v"(c6));
    asm("v_permlane32_swap_b32 %0, %1" : "+v"(c5), "+v"(c7));
    unsigned d0 = cvt_pk_bf16(pd[0],  pd[1]),  d1 = cvt_pk_bf16(pd[2],  pd[3]);
    unsigned d2 = cvt_pk_bf16(pd[4],  pd[5]),  d3 = cvt_pk_bf16(pd[6],  pd[7]);
    unsigned d4 = cvt_pk_bf16(pd[8],  pd[9]),  d5 = cvt_pk_bf16(pd[10], pd[11]);
    unsigned d6 = cvt_pk_bf16(pd[12], pd[13]), d7 = cvt_pk_bf16(pd[14], pd[15]);
    asm("v_permlane32_swap_b32 %0, %1" : "+v"(d0), "+v"(d2));
    asm("v_permlane32_swap_b32 %0, %1" : "+v"(d1), "+v"(d3));
    asm("v_permlane32_swap_b32 %0, %1" : "+v"(d4), "+v"(d6));
    asm("v_permlane32_swap_b32 %0, %1" : "+v"(d5), "+v"(d7));
    union { unsigned u[4]; bf16x8 v; } fc0, fc1, fd0, fd1;
    fc0.u[0] = c0; fc0.u[1] = c1; fc0.u[2] = c2; fc0.u[3] = c3;
    fc1.u[0] = c4; fc1.u[1] = c5; fc1.u[2] = c6; fc1.u[3] = c7;
    fd0.u[0] = d0; fd0.u[1] = d1; fd0.u[2] = d2; fd0.u[3] = d3;
    fd1.u[0] = d4; fd1.u[1] = d5; fd1.u[2] = d6; fd1.u[3] = d7;
    oc = __builtin_amdgcn_mfma_f32_32x32x16_bf16(fc0.v, vf0, oc, 0, 0, 0);
    oc = __builtin_amdgcn_mfma_f32_32x32x16_bf16(fc1.v, vf1, oc, 0, 0, 0);
    od = __builtin_amdgcn_mfma_f32_32x32x16_bf16(fd0.v, vf0, od, 0, 0, 0);
    od = __builtin_amdgcn_mfma_f32_32x32x16_bf16(fd1.v, vf1, od, 0, 0, 0);

    kf0 = nk0; kf1 = nk1; vf0 = nv0; vf1 = nv1;
  }

  // lane-pair combine of l (lane and lane^32 hold complementary m rows)
  float lsA = (la[0] + la[1]) + (la[2] + la[3]);
  float lsB = (lb[0] + lb[1]) + (lb[2] + lb[3]);
  float lsC = (lc[0] + lc[1]) + (lc[2] + lc[3]);
  float lsD = (ld[0] + ld[1]) + (ld[2] + ld[3]);
  lsA += __shfl_xor(lsA, 32, 64);
  lsB += __shfl_xor(lsB, 32, 64);
  lsC += __shfl_xor(lsC, 32, 64);
  lsD += __shfl_xor(lsD, 32, 64);

  // ---- combine m-quarters (linear: static softmax -> no rescale) ----
  if (wave) {
    float* Cb = &Comb[wave - 1][lane][0];
#pragma unroll
    for (int r = 0; r < 16; r++) {
      Cb[r] = oa[r]; Cb[16 + r] = ob[r]; Cb[32 + r] = oc[r]; Cb[48 + r] = od[r];
    }
    Cb[64] = lsA; Cb[65] = lsB; Cb[66] = lsC; Cb[67] = lsD;
  }
  __syncthreads();
  if (wave == 0) {
#pragma unroll
    for (int w = 0; w < 3; w++) {
      const float* Cb = &Comb[w][lane][0];
#pragma unroll
      for (int r = 0; r < 16; r++) {
        oa[r] += Cb[r]; ob[r] += Cb[16 + r]; oc[r] += Cb[32 + r]; od[r] += Cb[48 + r];
      }
      lsA += Cb[64]; lsB += Cb[65]; lsC += Cb[66]; lsD += Cb[67];
    }
    if (hi == 0) {
      Linv[0][l31] = 1.0f / lsA;    // same-wave RAW: compiler waits
      Linv[1][l31] = 1.0f / lsB;
      Linv[2][l31] = 1.0f / lsC;
      Linv[3][l31] = 1.0f / lsD;
    }
    // O[n = n0+tile*32+crow(r,hi), d = l31] -> at[b, n, c = d*8 + h]
    unsigned short* ab = at + (size_t)b * NP * NC + (size_t)(l31 * 8 + h);
#pragma unroll
    for (int r = 0; r < 16; r++) {
      int crow = (r & 3) + 8 * (r >> 2) + 4 * hi;
      ab[(size_t)(n0 + crow) * NC]       = f2b1(oa[r] * Linv[0][crow]);
      ab[(size_t)(n0 + 32 + crow) * NC]  = f2b1(ob[r] * Linv[1][crow]);
      ab[(size_t)(n0 + 64 + crow) * NC]  = f2b1(oc[r] * Linv[2][crow]);
      ab[(size_t)(n0 + 96 + crow) * NC]  = f2b1(od[r] * Linv[3][crow]);
    }
  }
}

// ---------------- output projection (64o x 128p) ----------------
__global__ __launch_bounds__(256) void mproj_kernel(
    const unsigned short* __restrict__ Wmb, const float* __restrict__ bm,
    const unsigned short* __restrict__ at, float* __restrict__ out) {
  int b = blockIdx.y, bx = blockIdx.x;
  int ot = (bx & 3) * 64, pt = (bx >> 2) * 128;    // 4 o-tiles x 8 p-tiles
  int tid = threadIdx.x, wave = tid >> 6, lane = tid & 63;
  int l15 = lane & 15, quad = lane >> 4;
  int oW = ot + (wave & 1) * 32, pW = pt + (wave >> 1) * 64;  // 32o x 64p
  const unsigned short* A0 = Wmb + (size_t)(oW + l15) * NC + quad * 8;
  const unsigned short* B0 = at + ((size_t)b * NP + pW + l15) * NC + quad * 8;
  f32x4 acc[2][4];
#pragma unroll
  for (int i = 0; i < 2; i++)
#pragma unroll
    for (int j = 0; j < 4; j++) acc[i][j] = (f32x4){0.f, 0.f, 0.f, 0.f};
#pragma unroll
  for (int c0 = 0; c0 < NC; c0 += 32) {
    bf16x8 a0 = *(const bf16x8*)(A0 + c0);
    bf16x8 a1 = *(const bf16x8*)(A0 + 16 * NC + c0);
    bf16x8 bb0 = *(const bf16x8*)(B0 + c0);
    bf16x8 bb1 = *(const bf16x8*)(B0 + 16 * NC + c0);
    bf16x8 bb2 = *(const bf16x8*)(B0 + 32 * NC + c0);
    bf16x8 bb3 = *(const bf16x8*)(B0 + 48 * NC + c0);
    acc[0][0] = __builtin_amdgcn_mfma_f32_16x16x32_bf16(a0, bb0, acc[0][0], 0, 0, 0);
    acc[0][1] = __builtin_amdgcn_mfma_f32_16x16x32_bf16(a0, bb1, acc[0][1], 0, 0, 0);
    acc[0][2] = __builtin_amdgcn_mfma_f32_16x16x32_bf16(a0, bb2, acc[0][2], 0, 0, 0);
    acc[0][3] = __builtin_amdgcn_mfma_f32_16x16x32_bf16(a0, bb3, acc[0][3], 0, 0, 0);
    acc[1][0] = __builtin_amdgcn_mfma_f32_16x16x32_bf16(a1, bb0, acc[1][0], 0, 0, 0);
    acc[1][1] = __builtin_amdgcn_mfma_f32_16x16x32_bf16(a1, bb1, acc[1][1], 0, 0, 0);
    acc[1][2] = __builtin_amdgcn_mfma_f32_16x16x32_bf16(a1, bb2, acc[1][2], 0, 0, 0);
    acc[1][3] = __builtin_amdgcn_mfma_f32_16x16x32_bf16(a1, bb3, acc[1][3], 0, 0, 0);
  }
#pragma unroll
  for (int rh = 0; rh < 2; rh++) {
    int od0 = oW + rh * 16 + quad * 4;
    float b0 = bm[od0], b1 = bm[od0+1], b2 = bm[od0+2], b3 = bm[od0+3];
#pragma unroll
    for (int ch = 0; ch < 4; ch++) {
      int p = pW + ch * 16 + l15;
      size_t base = ((size_t)b * NC + od0) * NP + p;
      out[base]          = acc[rh][ch][0] + b0;
      out[base +     NP] = acc[rh][ch][1] + b1;
      out[base + 2 * NP] = acc[rh][ch][2] + b2;
      out[base + 3 * NP] = acc[rh][ch][3] + b3;
    }
  }
}

extern "C" void kernel_launch(void* const* d_in, const int* in_sizes, int n_in,
                              void* d_out, int out_size, void* d_ws, size_t ws_size,
                              hipStream_t stream) {
  (void)in_sizes; (void)n_in; (void)out_size; (void)ws_size;
  const float* x  = (const float*)d_in[0];
  const float* Wq = (const float*)d_in[1];
  const float* bq = (const float*)d_in[2];
  const float* Wk = (const float*)d_in[3];
  const float* bk = (const float*)d_in[4];
  const float* Wv = (const float*)d_in[5];
  const float* bv = (const float*)d_in[6];
  const float* Wm = (const float*)d_in[7];
  const float* bm = (const float*)d_in[8];
  float* out = (float*)d_out;
  char* ws = (char*)d_ws;

  unsigned short* xt = (unsigned short*)(ws);                              // 4 MB
  unsigned short* Wb = (unsigned short*)(ws + (4u << 20));                 // 512 KB
  unsigned short* qt = (unsigned short*)(ws + (4u << 20) + (512u << 10));  // 4 MB
  unsigned short* kt = (unsigned short*)(ws + (8u << 20) + (512u << 10));  // 4 MB
  unsigned short* vt = (unsigned short*)(ws + (12u << 20) + (512u << 10)); // 4 MB
  unsigned short* at = (unsigned short*)(ws + (16u << 20) + (512u << 10)); // 4 MB

  prep_kernel<<<640, 256, 0, stream>>>(Wq, Wk, Wv, Wm, x, Wb, xt);
  qkv_kernel<<<dim3(32, 8), 256, 0, stream>>>(Wb, bq, bk, bv, xt, qt, kt, vt);
  attn_kernel<<<dim3(8, 64), 256, 0, stream>>>(qt, kt, vt, at);
  mproj_kernel<<<dim3(32, 8), 256, 0, stream>>>(Wb + 3 * 65536, bm, at, out);
}